// Round 12
// baseline (2568.680 us; speedup 1.0000x reference)
//
#include <hip/hip_runtime.h>

#define NB 1024   // batch
#define TT 32     // encoder length
#define DIN 256   // input dim
#define HD 256    // hidden dim
#define NC 38     // classes
#define NSTEP 26  // decode steps

typedef unsigned short ushort_t;
typedef __attribute__((ext_vector_type(8))) short bf16x8;
typedef __attribute__((ext_vector_type(8))) unsigned short us8;
typedef __attribute__((ext_vector_type(4))) float f32x4;

#define GLOAD_LDS16(g, l) \
  __builtin_amdgcn_global_load_lds((const __attribute__((address_space(1))) unsigned int*)(g), \
                                   (__attribute__((address_space(3))) unsigned int*)(l), 16, 0, 0)

__device__ __forceinline__ unsigned short f2bf(float x) {
    union { float f; unsigned u; } v; v.f = x;
    unsigned r = v.u + 0x7fff + ((v.u >> 16) & 1);   // RNE
    return (unsigned short)(r >> 16);
}
__device__ __forceinline__ float bf2f(unsigned short h) {
    union { unsigned u; float f; } v; v.u = ((unsigned)h) << 16;
    return v.f;
}
__device__ __forceinline__ float fast_tanh(float x) {
    float xc = fminf(fmaxf(x, -15.f), 15.f);
    float z = __expf(2.f * xc);
    return (z - 1.f) * __builtin_amdgcn_rcpf(z + 1.f);
}
__device__ __forceinline__ float fast_sig(float x) {
    return __builtin_amdgcn_rcpf(1.f + __expf(-x));
}

// ---------------------------------------------------------------------------
// prep_all: 3585 blocks (proven).
// ---------------------------------------------------------------------------
__global__ __launch_bounds__(256) void prep_all(
    const float* __restrict__ w_ih, const float* __restrict__ w_hh,
    const float* __restrict__ w_i2h, const float* __restrict__ w_h2h,
    const float* __restrict__ enc,
    ushort_t* __restrict__ B2g, ushort_t* __restrict__ B2i,
    ushort_t* __restrict__ w2hb, ushort_t* __restrict__ encA2,
    int* __restrict__ cnt)
{
    const int bid = blockIdx.x, tid = threadIdx.x;
    if (bid < 1024) {
        int j = bid;
        for (int k = tid; k < 512; k += 256) {
            float x = (k < 256) ? w_ih[(size_t)j * 294 + k] : w_hh[(size_t)j * 256 + (k - 256)];
            unsigned short hi = f2bf(x);
            unsigned short lo = f2bf(x - bf2f(hi));
            size_t r = (size_t)j * 1536;
            B2g[r + k] = hi; B2g[r + 512 + k] = lo; B2g[r + 1024 + k] = hi;
        }
    } else if (bid < 1280) {
        int n = bid - 1024;
        float x = w_i2h[(size_t)n * 256 + tid];
        unsigned short hi = f2bf(x);
        unsigned short lo = f2bf(x - bf2f(hi));
        size_t r = (size_t)n * 768;
        B2i[r + tid] = hi; B2i[r + 256 + tid] = lo; B2i[r + 512 + tid] = hi;
    } else if (bid < 1536) {
        int j = bid - 1280;
        w2hb[(size_t)j * 256 + tid] = f2bf(w_h2h[(size_t)j * 256 + tid]);
    } else if (bid < 3584) {
        int base = (bid - 1536) * 16;
#pragma unroll
        for (int rr = 0; rr < 16; rr++) {
            size_t row = base + rr;
            float x = enc[row * 256 + tid];
            unsigned short hi = f2bf(x);
            unsigned short lo = f2bf(x - bf2f(hi));
            encA2[row * 512 + tid] = hi;
            encA2[row * 512 + 256 + tid] = lo;
        }
    } else {
        for (int k = tid; k < NSTEP * 16; k += 256) cnt[k] = 0;
    }
}

// ---------------------------------------------------------------------------
// hproj_pipe: Hb[m][n] = bf16( sum_k enc[m][k]*w_i2h[n][k] )   (proven)
// ---------------------------------------------------------------------------
__global__ __launch_bounds__(256) void hproj_pipe(
    const ushort_t* __restrict__ encA2, const ushort_t* __restrict__ B2i,
    ushort_t* __restrict__ Hb)
{
    __shared__ ushort_t lA[2][64 * 128];
    __shared__ ushort_t lB[2][64 * 128];

    const int tid = threadIdx.x;
    const int lane = tid & 63, wid = tid >> 6;
    const int wm = wid >> 1, wn = wid & 1;
    const int m0 = blockIdx.x * 64, n0 = blockIdx.y * 64;

    f32x4 acc[2][2];
    const f32x4 fz = {0.f, 0.f, 0.f, 0.f};
    acc[0][0] = fz; acc[0][1] = fz; acc[1][0] = fz; acc[1][1] = fz;

    auto stage = [&](int t, int buf) {
#pragma unroll
        for (int i = 0; i < 4; i++) {
            int cpos = tid + i * 256;
            int m = cpos >> 4, p = cpos & 15;
            int g = p ^ (m & 7);
            int vk = t * 128 + g * 8;
            int acol = (vk < 256) ? vk : vk - 256;
            GLOAD_LDS16(&encA2[(size_t)(m0 + m) * 512 + acol], &lA[buf][cpos * 8]);
        }
#pragma unroll
        for (int i = 0; i < 4; i++) {
            int cpos = tid + i * 256;
            int n = cpos >> 4, p = cpos & 15;
            int g = p ^ (n & 7);
            GLOAD_LDS16(&B2i[(size_t)(n0 + n) * 768 + t * 128 + g * 8], &lB[buf][cpos * 8]);
        }
    };

    stage(0, 0);
    stage(1, 1);

    for (int t = 0; t < 6; t++) {
        int cur = t & 1;
        if (t < 5) asm volatile("s_waitcnt vmcnt(8)" ::: "memory");
        else       asm volatile("s_waitcnt vmcnt(0)" ::: "memory");
        __syncthreads();
#pragma unroll
        for (int kk = 0; kk < 4; kk++) {
            int g = kk * 4 + (lane >> 4);
            bf16x8 af[2], bfr[2];
#pragma unroll
            for (int mi = 0; mi < 2; mi++) {
                int m = wm * 32 + mi * 16 + (lane & 15);
                af[mi] = *(const bf16x8*)&lA[cur][m * 128 + ((g ^ (m & 7)) << 3)];
            }
#pragma unroll
            for (int ni = 0; ni < 2; ni++) {
                int n = wn * 32 + ni * 16 + (lane & 15);
                bfr[ni] = *(const bf16x8*)&lB[cur][n * 128 + ((g ^ (n & 7)) << 3)];
            }
#pragma unroll
            for (int mi = 0; mi < 2; mi++)
#pragma unroll
                for (int ni = 0; ni < 2; ni++)
                    acc[mi][ni] = __builtin_amdgcn_mfma_f32_16x16x32_bf16(af[mi], bfr[ni], acc[mi][ni], 0, 0, 0);
        }
        __syncthreads();
        if (t + 2 < 6) stage(t + 2, cur);
    }

    const int r4 = (lane >> 4) * 4;
#pragma unroll
    for (int mi = 0; mi < 2; mi++)
#pragma unroll
        for (int r = 0; r < 4; r++) {
            size_t row = m0 + wm * 32 + mi * 16 + r4 + r;
#pragma unroll
            for (int ni = 0; ni < 2; ni++) {
                int col = n0 + wn * 32 + ni * 16 + (lane & 15);
                Hb[row * 256 + col] = f2bf(acc[mi][ni][r]);
            }
        }
}

// ---------------------------------------------------------------------------
// fused_step: ONE dispatch per decode step, ALL 1280 blocks co-resident
// (LDS exactly 32 KB -> 5 blocks/CU x 256 CU = 1280).
//   blocks [0,1024):   attn role (scratch folded inside lA's 16 KB)
//   blocks [1024,1280): gates role, 64x64 tile, BK=64 dbuf, counted vmcnt
// ---------------------------------------------------------------------------
__global__ __launch_bounds__(256, 5) void fused_step(
    const ushort_t* __restrict__ Hb, const ushort_t* __restrict__ encA2,
    const ushort_t* __restrict__ B2g, const ushort_t* __restrict__ w2hb,
    const float* __restrict__ b_h2h,
    const float* __restrict__ w_gen, const float* __restrict__ b_gen,
    const float* __restrict__ w_score,
    const float* __restrict__ b_ih, const float* __restrict__ b_hh,
    const float* __restrict__ w_ih, const int* __restrict__ text,
    float* __restrict__ c, ushort_t* __restrict__ A2,
    float* __restrict__ gates, float* __restrict__ probs,
    int* __restrict__ cnt, int step)
{
    __shared__ ushort_t lA[2][64 * 64];   // 16 KB
    __shared__ ushort_t lB[2][64 * 64];   // 16 KB  -> total 32 KB

    const int tid = threadIdx.x;
    const int bid = blockIdx.x;

    if (bid < 1024) {
        // =================== attn role (scratch inside lA, 11.4 KB) =========
        float* hsh  = (float*)&lA[0][0];     // 256 f
        float* hpsh = hsh + 256;             // 256 f
        float* wssh = hpsh + 256;            // 256 f
        float* esh  = wssh + 256;            // 32 f
        float* psh  = esh + 32;              // [8][257] f

        const int b = (bid & 7) * 128 + (bid >> 3);

        // prefetch register slices (no dependencies -> issue immediately)
        us8 hb0, hb1, hb2, hb3, eb0, eb1, eb2, eb3;
        if (step < NSTEP) {
            const ushort_t* hr = &Hb[((size_t)b * TT + (tid >> 3)) * HD + (tid & 7) * 8];
            hb0 = *(const us8*)&hr[0];
            hb1 = *(const us8*)&hr[64];
            hb2 = *(const us8*)&hr[128];
            hb3 = *(const us8*)&hr[192];
            const ushort_t* er = &encA2[((size_t)b * TT + (tid >> 5) * 4) * 512 + (tid & 31) * 8];
            eb0 = *(const us8*)&er[0];
            eb1 = *(const us8*)&er[512];
            eb2 = *(const us8*)&er[1024];
            eb3 = *(const us8*)&er[1536];
        }

        wssh[tid] = w_score[tid];

        if (step > 0) {
            const float* g = &gates[(size_t)b * 1024];
            float gi = g[tid];
            float gf = g[256 + tid];
            float gg = g[512 + tid];
            float go = g[768 + tid];
            float cv = c[(size_t)b * HD + tid];
            float cn = fast_sig(gf) * cv + fast_sig(gi) * fast_tanh(gg);
            float hn = fast_sig(go) * fast_tanh(cn);
            c[(size_t)b * HD + tid] = cn;
            hsh[tid] = hn;
            if (step < NSTEP) {
                unsigned short hi_ = f2bf(hn);
                A2[(size_t)b * 1024 + 256 + tid] = hi_;
                A2[(size_t)b * 1024 + 768 + tid] = f2bf(hn - bf2f(hi_));
            }
            __syncthreads();
            if (tid < 4 * NC) {
                int jj = tid >> 2, q = tid & 3;
                const float* wg = &w_gen[(size_t)jj * HD + q * 64];
                const float* hv = &hsh[q * 64];
                float s = 0.f;
#pragma unroll
                for (int d = 0; d < 64; d += 4) {
                    float4 wv = *(const float4*)&wg[d];
                    float4 hq = *(const float4*)&hv[d];
                    s += wv.x * hq.x + wv.y * hq.y + wv.z * hq.z + wv.w * hq.w;
                }
                s += __shfl_xor(s, 1);
                s += __shfl_xor(s, 2);
                if (q == 0)
                    probs[((size_t)b * NSTEP + (step - 1)) * NC + jj] = s + b_gen[jj];
            }
        } else {
            hsh[tid] = 0.f;
            c[(size_t)b * HD + tid] = 0.f;
            A2[(size_t)b * 1024 + 256 + tid] = 0;
            A2[(size_t)b * 1024 + 768 + tid] = 0;
            __syncthreads();
        }
        if (step >= NSTEP) return;

        // hp
        {
            float a = 0.f;
            const ushort_t* wr = &w2hb[(size_t)tid * HD];
#pragma unroll 4
            for (int d = 0; d < HD; d += 8) {
                us8 wv = *(const us8*)&wr[d];
#pragma unroll
                for (int k = 0; k < 8; k++)
                    a += bf2f(wv[k]) * hsh[d + k];
            }
            hpsh[tid] = a + b_h2h[tid];
        }
        __syncthreads();

        // scores
        {
            int sl = tid & 7;
            float e = 0.f;
#define DOT8(hbv, base) { us8 hv_ = hbv; \
  _Pragma("unroll") for (int k = 0; k < 8; k++) { int d_ = (base) + k; \
      e += wssh[d_] * fast_tanh(bf2f(hv_[k]) + hpsh[d_]); } }
            DOT8(hb0, sl * 8)
            DOT8(hb1, sl * 8 + 64)
            DOT8(hb2, sl * 8 + 128)
            DOT8(hb3, sl * 8 + 192)
#undef DOT8
            e += __shfl_xor(e, 4);
            e += __shfl_xor(e, 2);
            e += __shfl_xor(e, 1);
            if (sl == 0) esh[tid >> 3] = e;
        }
        __syncthreads();

        // softmax over 32 t
        if (tid < 32) {
            float v = esh[tid];
            float m = v;
#pragma unroll
            for (int o = 16; o > 0; o >>= 1) m = fmaxf(m, __shfl_xor(m, o));
            float p = __expf(v - m);
            float ssum = p;
#pragma unroll
            for (int o = 16; o > 0; o >>= 1) ssum += __shfl_xor(ssum, o);
            esh[tid] = p * __builtin_amdgcn_rcpf(ssum);
        }
        __syncthreads();

        // context
        {
            int gq = tid >> 5;
            float pp[8] = {0.f, 0.f, 0.f, 0.f, 0.f, 0.f, 0.f, 0.f};
#define CTXACC(ebv, tt) { float a_ = esh[gq * 4 + (tt)]; us8 ev_ = ebv; \
  _Pragma("unroll") for (int k = 0; k < 8; k++) pp[k] += a_ * bf2f(ev_[k]); }
            CTXACC(eb0, 0) CTXACC(eb1, 1) CTXACC(eb2, 2) CTXACC(eb3, 3)
#undef CTXACC
            int l = tid & 31;
#pragma unroll
            for (int k = 0; k < 8; k++)
                psh[gq * 257 + l * 8 + k] = pp[k];
        }
        __syncthreads();
        {
            float a = 0.f;
#pragma unroll
            for (int gq = 0; gq < 8; gq++)
                a += psh[gq * 257 + tid];
            unsigned short hi_ = f2bf(a);
            A2[(size_t)b * 1024 + tid] = hi_;
            A2[(size_t)b * 1024 + 512 + tid] = f2bf(a - bf2f(hi_));
        }

        __syncthreads();
        if (tid == 0) {
            __threadfence();
            atomicAdd(&cnt[step * 16 + (b >> 6)], 1);
        }
        return;
    }

    // =================== gates role ===================
    if (step >= NSTEP) return;

    const int gid = bid - 1024;
    const int xcd = gid & 7, j = gid >> 3;
    const int m0 = (j >> 1) * 64;
    const int n0 = (xcd * 2 + (j & 1)) * 64;
    const int lane = tid & 63, wid = tid >> 6;
    const int wm = wid >> 1, wn = wid & 1;

    f32x4 acc[2][2];
    const f32x4 fz = {0.f, 0.f, 0.f, 0.f};
    acc[0][0] = fz; acc[0][1] = fz; acc[1][0] = fz; acc[1][1] = fz;

    // stage: 64 rows x 64 ush per tile; 512 chunks of 8 ush; 2 per thread
    auto stageA = [&](int t, int buf) {
#pragma unroll
        for (int i = 0; i < 2; i++) {
            int cpos = tid + i * 256;
            int m = cpos >> 3, p = cpos & 7;
            int g = p ^ (m & 7);
            int vk = t * 64 + g * 8;
            int acol = (vk < 512) ? vk : vk - 512;
            GLOAD_LDS16(&A2[(size_t)(m0 + m) * 1024 + acol], &lA[buf][cpos * 8]);
        }
    };
    auto stageB = [&](int t, int buf) {
#pragma unroll
        for (int i = 0; i < 2; i++) {
            int cpos = tid + i * 256;
            int n = cpos >> 3, p = cpos & 7;
            int g = p ^ (n & 7);
            GLOAD_LDS16(&B2g[(size_t)(n0 + n) * 1536 + t * 64 + g * 8], &lB[buf][cpos * 8]);
        }
    };

    // B read-only: prefetch before the wait (hides under spin)
    stageB(0, 0);
    stageB(1, 1);

    if (tid == 0) {
        int* flag = &cnt[step * 16 + (m0 >> 6)];
        while (atomicAdd(flag, 0) < 64)
            __builtin_amdgcn_s_sleep(4);
        __threadfence();   // acquire before reading A2
    }
    __syncthreads();

    stageA(0, 0);
    stageA(1, 1);

    for (int t = 0; t < 24; t++) {
        int cur = t & 1;
        // issue order: B0,B1 (pre-spin), A0,A1; then per-iter A(t+2),B(t+2).
        if (t == 0)      asm volatile("s_waitcnt vmcnt(2)" ::: "memory");  // A0 done
        else if (t < 23) asm volatile("s_waitcnt vmcnt(4)" ::: "memory");  // stage(t) done
        else             asm volatile("s_waitcnt vmcnt(0)" ::: "memory");
        __syncthreads();
#pragma unroll
        for (int kk = 0; kk < 2; kk++) {
            int g = kk * 4 + (lane >> 4);
            bf16x8 af[2], bfr[2];
#pragma unroll
            for (int mi = 0; mi < 2; mi++) {
                int m = wm * 32 + mi * 16 + (lane & 15);
                af[mi] = *(const bf16x8*)&lA[cur][m * 64 + ((g ^ (m & 7)) << 3)];
            }
#pragma unroll
            for (int ni = 0; ni < 2; ni++) {
                int n = wn * 32 + ni * 16 + (lane & 15);
                bfr[ni] = *(const bf16x8*)&lB[cur][n * 64 + ((g ^ (n & 7)) << 3)];
            }
#pragma unroll
            for (int mi = 0; mi < 2; mi++)
#pragma unroll
                for (int ni = 0; ni < 2; ni++)
                    acc[mi][ni] = __builtin_amdgcn_mfma_f32_16x16x32_bf16(af[mi], bfr[ni], acc[mi][ni], 0, 0, 0);
        }
        __syncthreads();
        if (t + 2 < 24) { stageA(t + 2, cur); stageB(t + 2, cur); }
    }

    const int r4 = (lane >> 4) * 4;
#pragma unroll
    for (int mi = 0; mi < 2; mi++)
#pragma unroll
        for (int r = 0; r < 4; r++) {
            int row = m0 + wm * 32 + mi * 16 + r4 + r;
            int cl = text[row * NSTEP + step];
#pragma unroll
            for (int ni = 0; ni < 2; ni++) {
                int col = n0 + wn * 32 + ni * 16 + (lane & 15);
                float v = acc[mi][ni][r] + b_ih[col] + b_hh[col]
                        + w_ih[(size_t)col * 294 + 256 + cl];
                gates[(size_t)row * 1024 + col] = v;
            }
        }
}

// ---------------------------------------------------------------------------
extern "C" void kernel_launch(void* const* d_in, const int* in_sizes, int n_in,
                              void* d_out, int out_size, void* d_ws, size_t ws_size,
                              hipStream_t stream)
{
    const float* enc     = (const float*)d_in[0];
    const int*   text    = (const int*)d_in[1];
    const float* w_i2h   = (const float*)d_in[4];
    const float* w_h2h   = (const float*)d_in[5];
    const float* b_h2h   = (const float*)d_in[6];
    const float* w_score = (const float*)d_in[7];
    const float* w_ih    = (const float*)d_in[8];
    const float* w_hh    = (const float*)d_in[9];
    const float* b_ih    = (const float*)d_in[10];
    const float* b_hh    = (const float*)d_in[11];
    const float* w_gen   = (const float*)d_in[12];
    const float* b_gen   = (const float*)d_in[13];
    float* out = (float*)d_out;

    const size_t MB = 1024 * 1024;
    char* ws = (char*)d_ws;
    ushort_t* Hb    = (ushort_t*)ws;                          // 16 MB  [0,16)
    ushort_t* B2g   = (ushort_t*)(ws + 16 * MB);              // 3 MB   [16,19)
    ushort_t* B2i   = (ushort_t*)(ws + 19 * MB);              // 384 KB
    ushort_t* w2hb  = (ushort_t*)(ws + 19 * MB + 512 * 1024); // 128 KB
    float*    cbuf  = (float*)(ws + 20 * MB);                 // 1 MB   [20,21)
    ushort_t* A2    = (ushort_t*)(ws + 21 * MB);              // 2 MB   [21,23)
    float*    gates = (float*)(ws + 23 * MB);                 // 4 MB   [23,27)
    ushort_t* encA2 = (ushort_t*)(ws + 27 * MB);              // 32 MB  [27,59)
    int*      cnt   = (int*)(ws + 60 * MB);                   // 1.6 KB

    prep_all<<<3585, 256, 0, stream>>>(w_ih, w_hh, w_i2h, w_h2h, enc,
                                       B2g, B2i, w2hb, encA2, cnt);
    hproj_pipe<<<dim3(512, 4), 256, 0, stream>>>(encA2, B2i, Hb);

    for (int s = 0; s <= NSTEP; s++) {
        fused_step<<<1280, 256, 0, stream>>>(Hb, encA2, B2g, w2hb, b_h2h,
                                             w_gen, b_gen, w_score,
                                             b_ih, b_hh, w_ih, text,
                                             cbuf, A2, gates, out, cnt, s);
    }
}

// Round 14
// 1107.069 us; speedup vs baseline: 2.3203x; 2.3203x over previous
//
#include <hip/hip_runtime.h>

#define NB 1024   // batch
#define TT 32     // encoder length
#define DIN 256   // input dim
#define HD 256    // hidden dim
#define NC 38     // classes
#define NSTEP 26  // decode steps

typedef unsigned short ushort_t;
typedef __attribute__((ext_vector_type(8))) short bf16x8;
typedef __attribute__((ext_vector_type(8))) unsigned short us8;
typedef __attribute__((ext_vector_type(4))) float f32x4;

#define GLOAD_LDS16(g, l) \
  __builtin_amdgcn_global_load_lds((const __attribute__((address_space(1))) unsigned int*)(g), \
                                   (__attribute__((address_space(3))) unsigned int*)(l), 16, 0, 0)

__device__ __forceinline__ unsigned short f2bf(float x) {
    union { float f; unsigned u; } v; v.f = x;
    unsigned r = v.u + 0x7fff + ((v.u >> 16) & 1);   // RNE
    return (unsigned short)(r >> 16);
}
__device__ __forceinline__ float bf2f(unsigned short h) {
    union { unsigned u; float f; } v; v.u = ((unsigned)h) << 16;
    return v.f;
}
__device__ __forceinline__ float fast_tanh(float x) {
    float xc = fminf(fmaxf(x, -15.f), 15.f);
    float z = __expf(2.f * xc);
    return (z - 1.f) * __builtin_amdgcn_rcpf(z + 1.f);
}
__device__ __forceinline__ float fast_sig(float x) {
    return __builtin_amdgcn_rcpf(1.f + __expf(-x));
}

// ---------------------------------------------------------------------------
// prep_all: 3584 blocks.
//   [0,1024):    B2g row bid           [hi512|lo512|hi512] of [w_ih:256 | w_hh]
//   [1024,1280): B2i row bid-1024      [hi256|lo256|hi256] of w_i2h
//   [1280,1536): w2hb row bid-1280     bf16 w_h2h
//   [1536,3584): encA2 + encb, 16 rows each
// ---------------------------------------------------------------------------
__global__ __launch_bounds__(256) void prep_all(
    const float* __restrict__ w_ih, const float* __restrict__ w_hh,
    const float* __restrict__ w_i2h, const float* __restrict__ w_h2h,
    const float* __restrict__ enc,
    ushort_t* __restrict__ B2g, ushort_t* __restrict__ B2i,
    ushort_t* __restrict__ w2hb, ushort_t* __restrict__ encA2,
    ushort_t* __restrict__ encb)
{
    const int bid = blockIdx.x, tid = threadIdx.x;
    if (bid < 1024) {
        int j = bid;
        for (int k = tid; k < 512; k += 256) {
            float x = (k < 256) ? w_ih[(size_t)j * 294 + k] : w_hh[(size_t)j * 256 + (k - 256)];
            unsigned short hi = f2bf(x);
            unsigned short lo = f2bf(x - bf2f(hi));
            size_t r = (size_t)j * 1536;
            B2g[r + k] = hi; B2g[r + 512 + k] = lo; B2g[r + 1024 + k] = hi;
        }
    } else if (bid < 1280) {
        int n = bid - 1024;
        float x = w_i2h[(size_t)n * 256 + tid];
        unsigned short hi = f2bf(x);
        unsigned short lo = f2bf(x - bf2f(hi));
        size_t r = (size_t)n * 768;
        B2i[r + tid] = hi; B2i[r + 256 + tid] = lo; B2i[r + 512 + tid] = hi;
    } else if (bid < 1536) {
        int j = bid - 1280;
        w2hb[(size_t)j * 256 + tid] = f2bf(w_h2h[(size_t)j * 256 + tid]);
    } else {
        int base = (bid - 1536) * 16;
#pragma unroll
        for (int rr = 0; rr < 16; rr++) {
            size_t row = base + rr;
            float x = enc[row * 256 + tid];
            unsigned short hi = f2bf(x);
            unsigned short lo = f2bf(x - bf2f(hi));
            encA2[row * 512 + tid] = hi;
            encA2[row * 512 + 256 + tid] = lo;
            encb[row * 256 + tid] = hi;
        }
    }
}

// ---------------------------------------------------------------------------
// hproj_pipe: Hb[m][n] = bf16( sum_k enc[m][k]*w_i2h[n][k] )   (proven)
// ---------------------------------------------------------------------------
__global__ __launch_bounds__(256) void hproj_pipe(
    const ushort_t* __restrict__ encA2, const ushort_t* __restrict__ B2i,
    ushort_t* __restrict__ Hb)
{
    __shared__ ushort_t lA[2][64 * 128];
    __shared__ ushort_t lB[2][64 * 128];

    const int tid = threadIdx.x;
    const int lane = tid & 63, wid = tid >> 6;
    const int wm = wid >> 1, wn = wid & 1;
    const int m0 = blockIdx.x * 64, n0 = blockIdx.y * 64;

    f32x4 acc[2][2];
    const f32x4 fz = {0.f, 0.f, 0.f, 0.f};
    acc[0][0] = fz; acc[0][1] = fz; acc[1][0] = fz; acc[1][1] = fz;

    auto stage = [&](int t, int buf) {
#pragma unroll
        for (int i = 0; i < 4; i++) {
            int cpos = tid + i * 256;
            int m = cpos >> 4, p = cpos & 15;
            int g = p ^ (m & 7);
            int vk = t * 128 + g * 8;
            int acol = (vk < 256) ? vk : vk - 256;
            GLOAD_LDS16(&encA2[(size_t)(m0 + m) * 512 + acol], &lA[buf][cpos * 8]);
        }
#pragma unroll
        for (int i = 0; i < 4; i++) {
            int cpos = tid + i * 256;
            int n = cpos >> 4, p = cpos & 15;
            int g = p ^ (n & 7);
            GLOAD_LDS16(&B2i[(size_t)(n0 + n) * 768 + t * 128 + g * 8], &lB[buf][cpos * 8]);
        }
    };

    stage(0, 0);
    stage(1, 1);

    for (int t = 0; t < 6; t++) {
        int cur = t & 1;
        if (t < 5) asm volatile("s_waitcnt vmcnt(8)" ::: "memory");
        else       asm volatile("s_waitcnt vmcnt(0)" ::: "memory");
        __syncthreads();
#pragma unroll
        for (int kk = 0; kk < 4; kk++) {
            int g = kk * 4 + (lane >> 4);
            bf16x8 af[2], bfr[2];
#pragma unroll
            for (int mi = 0; mi < 2; mi++) {
                int m = wm * 32 + mi * 16 + (lane & 15);
                af[mi] = *(const bf16x8*)&lA[cur][m * 128 + ((g ^ (m & 7)) << 3)];
            }
#pragma unroll
            for (int ni = 0; ni < 2; ni++) {
                int n = wn * 32 + ni * 16 + (lane & 15);
                bfr[ni] = *(const bf16x8*)&lB[cur][n * 128 + ((g ^ (n & 7)) << 3)];
            }
#pragma unroll
            for (int mi = 0; mi < 2; mi++)
#pragma unroll
                for (int ni = 0; ni < 2; ni++)
                    acc[mi][ni] = __builtin_amdgcn_mfma_f32_16x16x32_bf16(af[mi], bfr[ni], acc[mi][ni], 0, 0, 0);
        }
        __syncthreads();
        if (t + 2 < 6) stage(t + 2, cur);
    }

    const int r4 = (lane >> 4) * 4;
#pragma unroll
    for (int mi = 0; mi < 2; mi++)
#pragma unroll
        for (int r = 0; r < 4; r++) {
            size_t row = m0 + wm * 32 + mi * 16 + r4 + r;
#pragma unroll
            for (int ni = 0; ni < 2; ni++) {
                int col = n0 + wn * 32 + ni * 16 + (lane & 15);
                Hb[row * 256 + col] = f2bf(acc[mi][ni][r]);
            }
        }
}

// ---------------------------------------------------------------------------
// gates_pipe: XCD-pinned 1D grid (256 blocks).  (verbatim round 7, proven)
// ---------------------------------------------------------------------------
__global__ __launch_bounds__(256) void gates_pipe(
    const ushort_t* __restrict__ A2, const ushort_t* __restrict__ B2,
    const float* __restrict__ b_ih, const float* __restrict__ b_hh,
    const float* __restrict__ w_ih, const int* __restrict__ text,
    int step, float* __restrict__ gates)
{
    __shared__ ushort_t lA[2][64 * 128];
    __shared__ ushort_t lB[2][64 * 128];

    const int tid = threadIdx.x;
    const int bid = blockIdx.x;
    const int xcd = bid & 7, j = bid >> 3;
    const int m0 = (j >> 1) * 64;
    const int n0 = (xcd * 2 + (j & 1)) * 64;
    const int lane = tid & 63, wid = tid >> 6;
    const int wm = wid >> 1, wn = wid & 1;

    f32x4 acc[2][2];
    const f32x4 fz = {0.f, 0.f, 0.f, 0.f};
    acc[0][0] = fz; acc[0][1] = fz; acc[1][0] = fz; acc[1][1] = fz;

    auto stage = [&](int t, int buf) {
#pragma unroll
        for (int i = 0; i < 4; i++) {
            int cpos = tid + i * 256;
            int m = cpos >> 4, p = cpos & 15;
            int g = p ^ (m & 7);
            int vk = t * 128 + g * 8;
            int acol = (vk < 512) ? vk : vk - 512;
            GLOAD_LDS16(&A2[(size_t)(m0 + m) * 1024 + acol], &lA[buf][cpos * 8]);
        }
#pragma unroll
        for (int i = 0; i < 4; i++) {
            int cpos = tid + i * 256;
            int n = cpos >> 4, p = cpos & 15;
            int g = p ^ (n & 7);
            GLOAD_LDS16(&B2[(size_t)(n0 + n) * 1536 + t * 128 + g * 8], &lB[buf][cpos * 8]);
        }
    };

    stage(0, 0);
    stage(1, 1);

    for (int t = 0; t < 12; t++) {
        int cur = t & 1;
        if (t < 11) asm volatile("s_waitcnt vmcnt(8)" ::: "memory");
        else        asm volatile("s_waitcnt vmcnt(0)" ::: "memory");
        __syncthreads();
#pragma unroll
        for (int kk = 0; kk < 4; kk++) {
            int g = kk * 4 + (lane >> 4);
            bf16x8 af[2], bfr[2];
#pragma unroll
            for (int mi = 0; mi < 2; mi++) {
                int m = wm * 32 + mi * 16 + (lane & 15);
                af[mi] = *(const bf16x8*)&lA[cur][m * 128 + ((g ^ (m & 7)) << 3)];
            }
#pragma unroll
            for (int ni = 0; ni < 2; ni++) {
                int n = wn * 32 + ni * 16 + (lane & 15);
                bfr[ni] = *(const bf16x8*)&lB[cur][n * 128 + ((g ^ (n & 7)) << 3)];
            }
#pragma unroll
            for (int mi = 0; mi < 2; mi++)
#pragma unroll
                for (int ni = 0; ni < 2; ni++)
                    acc[mi][ni] = __builtin_amdgcn_mfma_f32_16x16x32_bf16(af[mi], bfr[ni], acc[mi][ni], 0, 0, 0);
        }
        __syncthreads();
        if (t + 2 < 12) stage(t + 2, cur);
    }

    const int r4 = (lane >> 4) * 4;
#pragma unroll
    for (int mi = 0; mi < 2; mi++)
#pragma unroll
        for (int r = 0; r < 4; r++) {
            int row = m0 + wm * 32 + mi * 16 + r4 + r;
            int cl = text[row * NSTEP + step];
#pragma unroll
            for (int ni = 0; ni < 2; ni++) {
                int col = n0 + wn * 32 + ni * 16 + (lane & 15);
                float v = acc[mi][ni][r] + b_ih[col] + b_hh[col]
                        + w_ih[(size_t)col * 294 + 256 + cl];
                gates[(size_t)row * 1024 + col] = v;
            }
        }
}

// ---------------------------------------------------------------------------
// attn_full: LSTM(s-1) [+ hseq write] + hp + scores + softmax + ctx + A2.
// 1024 blocks x 256 threads, one row/block, XCD-pinned.  (round-7 body,
// probs phase removed -> hoisted to probs_final)
// ---------------------------------------------------------------------------
__global__ __launch_bounds__(256) void attn_full(
    const float* __restrict__ gates,
    const ushort_t* __restrict__ w2hb, const float* __restrict__ b_h2h,
    const float* __restrict__ w_score,
    const ushort_t* __restrict__ encb, const ushort_t* __restrict__ Hb,
    float* __restrict__ c, ushort_t* __restrict__ A2,
    float* __restrict__ hseq, int step)
{
    __shared__ float hsh[HD];
    __shared__ float hpsh[HD];
    __shared__ float wssh[HD];
    __shared__ float esh[TT];
    __shared__ float psh[8][HD + 1];

    const int tid = threadIdx.x;
    const int bid = blockIdx.x;
    const int b = (bid & 7) * 128 + (bid >> 3);

    wssh[tid] = w_score[tid];

    if (step > 0) {
        // LSTM(step-1): one element per thread
        const float* g = &gates[(size_t)b * 1024];
        float gi = g[tid];
        float gf = g[256 + tid];
        float gg = g[512 + tid];
        float go = g[768 + tid];
        float cv = c[(size_t)b * HD + tid];
        float cn = fast_sig(gf) * cv + fast_sig(gi) * fast_tanh(gg);
        float hn = fast_sig(go) * fast_tanh(cn);
        c[(size_t)b * HD + tid] = cn;
        hsh[tid] = hn;
        hseq[((size_t)(step - 1) * NB + b) * HD + tid] = hn;
        if (step < NSTEP) {
            unsigned short hi_ = f2bf(hn);
            A2[(size_t)b * 1024 + 256 + tid] = hi_;
            A2[(size_t)b * 1024 + 768 + tid] = f2bf(hn - bf2f(hi_));
        }
        __syncthreads();
    } else {
        // step 0: h = c = 0
        hsh[tid] = 0.f;
        c[(size_t)b * HD + tid] = 0.f;
        A2[(size_t)b * 1024 + 256 + tid] = 0;
        A2[(size_t)b * 1024 + 768 + tid] = 0;
        __syncthreads();
    }
    if (step >= NSTEP) return;

    // hp[j] = dot(w2hb[j], h) + b_h2h[j], j = tid  (hsh reads broadcast)
    {
        float a = 0.f;
        const ushort_t* wr = &w2hb[(size_t)tid * HD];
#pragma unroll 4
        for (int d = 0; d < HD; d += 8) {
            us8 wv = *(const us8*)&wr[d];
#pragma unroll
            for (int k = 0; k < 8; k++)
                a += bf2f(wv[k]) * hsh[d + k];
        }
        hpsh[tid] = a + b_h2h[tid];
    }
    __syncthreads();

    // scores: 8 threads per t, 32 d each (bf16 Hb)
    {
        int t = tid >> 3, sl = tid & 7;
        const ushort_t* hr = &Hb[((size_t)b * TT + t) * HD];
        float e = 0.f;
#pragma unroll
        for (int jj = 0; jj < 4; jj++) {
            int d0 = sl * 8 + jj * 64;
            us8 hv = *(const us8*)&hr[d0];
#pragma unroll
            for (int k = 0; k < 8; k++) {
                int d = d0 + k;
                e += wssh[d] * fast_tanh(bf2f(hv[k]) + hpsh[d]);
            }
        }
        e += __shfl_xor(e, 4);
        e += __shfl_xor(e, 2);
        e += __shfl_xor(e, 1);
        if (sl == 0) esh[t] = e;
    }
    __syncthreads();

    // softmax over 32 t
    if (tid < 32) {
        float v = esh[tid];
        float m = v;
#pragma unroll
        for (int o = 16; o > 0; o >>= 1) m = fmaxf(m, __shfl_xor(m, o));
        float p = __expf(v - m);
        float ssum = p;
#pragma unroll
        for (int o = 16; o > 0; o >>= 1) ssum += __shfl_xor(ssum, o);
        esh[tid] = p * __builtin_amdgcn_rcpf(ssum);
    }
    __syncthreads();

    // context from bf16 encb: group g=tid>>5 covers t in [4g,4g+4), 8 d/thread
    {
        int g = tid >> 5, l = tid & 31;
        float pp[8] = {0.f, 0.f, 0.f, 0.f, 0.f, 0.f, 0.f, 0.f};
#pragma unroll
        for (int tt = 0; tt < 4; tt++) {
            int t = g * 4 + tt;
            float a = esh[t];
            us8 ev = *(const us8*)&encb[((size_t)b * TT + t) * DIN + l * 8];
#pragma unroll
            for (int k = 0; k < 8; k++)
                pp[k] += a * bf2f(ev[k]);
        }
#pragma unroll
        for (int k = 0; k < 8; k++)
            psh[g][l * 8 + k] = pp[k];
    }
    __syncthreads();
    {
        float a = 0.f;
#pragma unroll
        for (int g = 0; g < 8; g++)
            a += psh[g][tid];
        unsigned short hi_ = f2bf(a);
        A2[(size_t)b * 1024 + tid] = hi_;
        A2[(size_t)b * 1024 + 512 + tid] = f2bf(a - bf2f(hi_));
    }
}

// ---------------------------------------------------------------------------
// probs_final: probs[b][s][j] = hseq[s][b] . w_gen[j] + b_gen[j]
// 1024 blocks (one batch row), 256 threads; h staged in LDS stride-257.
// 988 (s,j) pairs per block -> strided loop (FIX of round-13 bug).
// ---------------------------------------------------------------------------
__global__ __launch_bounds__(256) void probs_final(
    const float* __restrict__ hseq, const float* __restrict__ w_gen,
    const float* __restrict__ b_gen, float* __restrict__ probs)
{
    __shared__ float hsh[NSTEP * 257];   // 26.1 KB

    const int tid = threadIdx.x;
    const int b = blockIdx.x;

    for (int i = tid; i < NSTEP * HD; i += 256) {
        int s = i >> 8, d = i & 255;
        hsh[s * 257 + d] = hseq[((size_t)s * NB + b) * HD + d];
    }
    __syncthreads();

    for (int i = tid; i < NSTEP * NC; i += 256) {
        int s = i / NC, j = i - s * NC;
        const float* wg = &w_gen[(size_t)j * HD];
        const float* hv = &hsh[s * 257];
        float a = b_gen[j];
        for (int d = 0; d < HD; d += 4) {
            float4 wv = *(const float4*)&wg[d];
            a += wv.x * hv[d] + wv.y * hv[d + 1] + wv.z * hv[d + 2] + wv.w * hv[d + 3];
        }
        probs[((size_t)b * NSTEP + s) * NC + j] = a;
    }
}

// ---------------------------------------------------------------------------
extern "C" void kernel_launch(void* const* d_in, const int* in_sizes, int n_in,
                              void* d_out, int out_size, void* d_ws, size_t ws_size,
                              hipStream_t stream)
{
    const float* enc     = (const float*)d_in[0];
    const int*   text    = (const int*)d_in[1];
    const float* w_i2h   = (const float*)d_in[4];
    const float* w_h2h   = (const float*)d_in[5];
    const float* b_h2h   = (const float*)d_in[6];
    const float* w_score = (const float*)d_in[7];
    const float* w_ih    = (const float*)d_in[8];
    const float* w_hh    = (const float*)d_in[9];
    const float* b_ih    = (const float*)d_in[10];
    const float* b_hh    = (const float*)d_in[11];
    const float* w_gen   = (const float*)d_in[12];
    const float* b_gen   = (const float*)d_in[13];
    float* out = (float*)d_out;

    const size_t MB = 1024 * 1024;
    char* ws = (char*)d_ws;
    ushort_t* Hb    = (ushort_t*)ws;                          // 16 MB  [0,16)
    ushort_t* B2g   = (ushort_t*)(ws + 16 * MB);              // 3 MB   [16,19)
    ushort_t* B2i   = (ushort_t*)(ws + 19 * MB);              // 384 KB
    ushort_t* w2hb  = (ushort_t*)(ws + 19 * MB + 512 * 1024); // 128 KB
    float*    cbuf  = (float*)(ws + 20 * MB);                 // 1 MB   [20,21)
    ushort_t* A2    = (ushort_t*)(ws + 21 * MB);              // 2 MB   [21,23)
    float*    gates = (float*)(ws + 23 * MB);                 // 4 MB   [23,27)
    ushort_t* encA2 = (ushort_t*)(ws + 27 * MB);              // 32 MB  [27,59)
    float*    hseq  = (float*)(ws + 27 * MB);                 // 26 MB, overlays encA2 (dead after hproj)
    ushort_t* encb  = (ushort_t*)(ws + 59 * MB);              // 16 MB  [59,75)

    prep_all<<<3584, 256, 0, stream>>>(w_ih, w_hh, w_i2h, w_h2h, enc,
                                       B2g, B2i, w2hb, encA2, encb);
    hproj_pipe<<<dim3(512, 4), 256, 0, stream>>>(encA2, B2i, Hb);

    for (int s = 0; s < NSTEP; s++) {
        attn_full<<<1024, 256, 0, stream>>>(gates, w2hb, b_h2h, w_score,
                                            encb, Hb, cbuf, A2, hseq, s);
        gates_pipe<<<256, 256, 0, stream>>>(A2, B2g, b_ih, b_hh,
                                            w_ih, text, s, gates);
    }
    // final LSTM (writes hseq[25])
    attn_full<<<1024, 256, 0, stream>>>(gates, w2hb, b_h2h, w_score,
                                        encb, Hb, cbuf, A2, hseq, NSTEP);
    probs_final<<<1024, 256, 0, stream>>>(hseq, w_gen, b_gen, out);
}

// Round 15
// 1044.159 us; speedup vs baseline: 2.4600x; 1.0602x over previous
//
#include <hip/hip_runtime.h>

#define NB 1024   // batch
#define TT 32     // encoder length
#define DIN 256   // input dim
#define HD 256    // hidden dim
#define NC 38     // classes
#define NSTEP 26  // decode steps

typedef unsigned short ushort_t;
typedef __attribute__((ext_vector_type(8))) short bf16x8;
typedef __attribute__((ext_vector_type(8))) unsigned short us8;
typedef __attribute__((ext_vector_type(4))) float f32x4;

#define GLOAD_LDS16(g, l) \
  __builtin_amdgcn_global_load_lds((const __attribute__((address_space(1))) unsigned int*)(g), \
                                   (__attribute__((address_space(3))) unsigned int*)(l), 16, 0, 0)

__device__ __forceinline__ unsigned short f2bf(float x) {
    union { float f; unsigned u; } v; v.f = x;
    unsigned r = v.u + 0x7fff + ((v.u >> 16) & 1);   // RNE
    return (unsigned short)(r >> 16);
}
__device__ __forceinline__ float bf2f(unsigned short h) {
    union { unsigned u; float f; } v; v.u = ((unsigned)h) << 16;
    return v.f;
}
__device__ __forceinline__ float fast_tanh(float x) {
    float xc = fminf(fmaxf(x, -15.f), 15.f);
    float z = __expf(2.f * xc);
    return (z - 1.f) * __builtin_amdgcn_rcpf(z + 1.f);
}
__device__ __forceinline__ float fast_sig(float x) {
    return __builtin_amdgcn_rcpf(1.f + __expf(-x));
}

// ---------------------------------------------------------------------------
// prep_all: 3584 blocks.
//   [0,1024):    B2g row bid           [hi512|lo512|hi512] of [w_ih:256 | w_hh]
//   [1024,1280): B2i row bid-1024      [hi256|lo256|hi256] of w_i2h
//   [1280,1536): w2hb row bid-1280     bf16 w_h2h
//   [1536,3584): encA2 + encb, 16 rows each
// ---------------------------------------------------------------------------
__global__ __launch_bounds__(256) void prep_all(
    const float* __restrict__ w_ih, const float* __restrict__ w_hh,
    const float* __restrict__ w_i2h, const float* __restrict__ w_h2h,
    const float* __restrict__ enc,
    ushort_t* __restrict__ B2g, ushort_t* __restrict__ B2i,
    ushort_t* __restrict__ w2hb, ushort_t* __restrict__ encA2,
    ushort_t* __restrict__ encb)
{
    const int bid = blockIdx.x, tid = threadIdx.x;
    if (bid < 1024) {
        int j = bid;
        for (int k = tid; k < 512; k += 256) {
            float x = (k < 256) ? w_ih[(size_t)j * 294 + k] : w_hh[(size_t)j * 256 + (k - 256)];
            unsigned short hi = f2bf(x);
            unsigned short lo = f2bf(x - bf2f(hi));
            size_t r = (size_t)j * 1536;
            B2g[r + k] = hi; B2g[r + 512 + k] = lo; B2g[r + 1024 + k] = hi;
        }
    } else if (bid < 1280) {
        int n = bid - 1024;
        float x = w_i2h[(size_t)n * 256 + tid];
        unsigned short hi = f2bf(x);
        unsigned short lo = f2bf(x - bf2f(hi));
        size_t r = (size_t)n * 768;
        B2i[r + tid] = hi; B2i[r + 256 + tid] = lo; B2i[r + 512 + tid] = hi;
    } else if (bid < 1536) {
        int j = bid - 1280;
        w2hb[(size_t)j * 256 + tid] = f2bf(w_h2h[(size_t)j * 256 + tid]);
    } else {
        int base = (bid - 1536) * 16;
#pragma unroll
        for (int rr = 0; rr < 16; rr++) {
            size_t row = base + rr;
            float x = enc[row * 256 + tid];
            unsigned short hi = f2bf(x);
            unsigned short lo = f2bf(x - bf2f(hi));
            encA2[row * 512 + tid] = hi;
            encA2[row * 512 + 256 + tid] = lo;
            encb[row * 256 + tid] = hi;
        }
    }
}

// ---------------------------------------------------------------------------
// hproj_pipe: Hb[m][n] = bf16( sum_k enc[m][k]*w_i2h[n][k] )   (proven)
// ---------------------------------------------------------------------------
__global__ __launch_bounds__(256) void hproj_pipe(
    const ushort_t* __restrict__ encA2, const ushort_t* __restrict__ B2i,
    ushort_t* __restrict__ Hb)
{
    __shared__ ushort_t lA[2][64 * 128];
    __shared__ ushort_t lB[2][64 * 128];

    const int tid = threadIdx.x;
    const int lane = tid & 63, wid = tid >> 6;
    const int wm = wid >> 1, wn = wid & 1;
    const int m0 = blockIdx.x * 64, n0 = blockIdx.y * 64;

    f32x4 acc[2][2];
    const f32x4 fz = {0.f, 0.f, 0.f, 0.f};
    acc[0][0] = fz; acc[0][1] = fz; acc[1][0] = fz; acc[1][1] = fz;

    auto stage = [&](int t, int buf) {
#pragma unroll
        for (int i = 0; i < 4; i++) {
            int cpos = tid + i * 256;
            int m = cpos >> 4, p = cpos & 15;
            int g = p ^ (m & 7);
            int vk = t * 128 + g * 8;
            int acol = (vk < 256) ? vk : vk - 256;
            GLOAD_LDS16(&encA2[(size_t)(m0 + m) * 512 + acol], &lA[buf][cpos * 8]);
        }
#pragma unroll
        for (int i = 0; i < 4; i++) {
            int cpos = tid + i * 256;
            int n = cpos >> 4, p = cpos & 15;
            int g = p ^ (n & 7);
            GLOAD_LDS16(&B2i[(size_t)(n0 + n) * 768 + t * 128 + g * 8], &lB[buf][cpos * 8]);
        }
    };

    stage(0, 0);
    stage(1, 1);

    for (int t = 0; t < 6; t++) {
        int cur = t & 1;
        if (t < 5) asm volatile("s_waitcnt vmcnt(8)" ::: "memory");
        else       asm volatile("s_waitcnt vmcnt(0)" ::: "memory");
        __syncthreads();
#pragma unroll
        for (int kk = 0; kk < 4; kk++) {
            int g = kk * 4 + (lane >> 4);
            bf16x8 af[2], bfr[2];
#pragma unroll
            for (int mi = 0; mi < 2; mi++) {
                int m = wm * 32 + mi * 16 + (lane & 15);
                af[mi] = *(const bf16x8*)&lA[cur][m * 128 + ((g ^ (m & 7)) << 3)];
            }
#pragma unroll
            for (int ni = 0; ni < 2; ni++) {
                int n = wn * 32 + ni * 16 + (lane & 15);
                bfr[ni] = *(const bf16x8*)&lB[cur][n * 128 + ((g ^ (n & 7)) << 3)];
            }
#pragma unroll
            for (int mi = 0; mi < 2; mi++)
#pragma unroll
                for (int ni = 0; ni < 2; ni++)
                    acc[mi][ni] = __builtin_amdgcn_mfma_f32_16x16x32_bf16(af[mi], bfr[ni], acc[mi][ni], 0, 0, 0);
        }
        __syncthreads();
        if (t + 2 < 6) stage(t + 2, cur);
    }

    const int r4 = (lane >> 4) * 4;
#pragma unroll
    for (int mi = 0; mi < 2; mi++)
#pragma unroll
        for (int r = 0; r < 4; r++) {
            size_t row = m0 + wm * 32 + mi * 16 + r4 + r;
#pragma unroll
            for (int ni = 0; ni < 2; ni++) {
                int col = n0 + wn * 32 + ni * 16 + (lane & 15);
                Hb[row * 256 + col] = f2bf(acc[mi][ni][r]);
            }
        }
}

// ---------------------------------------------------------------------------
// gates_pipe: XCD-pinned 1D grid (256 blocks).  (verbatim round 7, proven)
// ---------------------------------------------------------------------------
__global__ __launch_bounds__(256) void gates_pipe(
    const ushort_t* __restrict__ A2, const ushort_t* __restrict__ B2,
    const float* __restrict__ b_ih, const float* __restrict__ b_hh,
    const float* __restrict__ w_ih, const int* __restrict__ text,
    int step, float* __restrict__ gates)
{
    __shared__ ushort_t lA[2][64 * 128];
    __shared__ ushort_t lB[2][64 * 128];

    const int tid = threadIdx.x;
    const int bid = blockIdx.x;
    const int xcd = bid & 7, j = bid >> 3;
    const int m0 = (j >> 1) * 64;
    const int n0 = (xcd * 2 + (j & 1)) * 64;
    const int lane = tid & 63, wid = tid >> 6;
    const int wm = wid >> 1, wn = wid & 1;

    f32x4 acc[2][2];
    const f32x4 fz = {0.f, 0.f, 0.f, 0.f};
    acc[0][0] = fz; acc[0][1] = fz; acc[1][0] = fz; acc[1][1] = fz;

    auto stage = [&](int t, int buf) {
#pragma unroll
        for (int i = 0; i < 4; i++) {
            int cpos = tid + i * 256;
            int m = cpos >> 4, p = cpos & 15;
            int g = p ^ (m & 7);
            int vk = t * 128 + g * 8;
            int acol = (vk < 512) ? vk : vk - 512;
            GLOAD_LDS16(&A2[(size_t)(m0 + m) * 1024 + acol], &lA[buf][cpos * 8]);
        }
#pragma unroll
        for (int i = 0; i < 4; i++) {
            int cpos = tid + i * 256;
            int n = cpos >> 4, p = cpos & 15;
            int g = p ^ (n & 7);
            GLOAD_LDS16(&B2[(size_t)(n0 + n) * 1536 + t * 128 + g * 8], &lB[buf][cpos * 8]);
        }
    };

    stage(0, 0);
    stage(1, 1);

    for (int t = 0; t < 12; t++) {
        int cur = t & 1;
        if (t < 11) asm volatile("s_waitcnt vmcnt(8)" ::: "memory");
        else        asm volatile("s_waitcnt vmcnt(0)" ::: "memory");
        __syncthreads();
#pragma unroll
        for (int kk = 0; kk < 4; kk++) {
            int g = kk * 4 + (lane >> 4);
            bf16x8 af[2], bfr[2];
#pragma unroll
            for (int mi = 0; mi < 2; mi++) {
                int m = wm * 32 + mi * 16 + (lane & 15);
                af[mi] = *(const bf16x8*)&lA[cur][m * 128 + ((g ^ (m & 7)) << 3)];
            }
#pragma unroll
            for (int ni = 0; ni < 2; ni++) {
                int n = wn * 32 + ni * 16 + (lane & 15);
                bfr[ni] = *(const bf16x8*)&lB[cur][n * 128 + ((g ^ (n & 7)) << 3)];
            }
#pragma unroll
            for (int mi = 0; mi < 2; mi++)
#pragma unroll
                for (int ni = 0; ni < 2; ni++)
                    acc[mi][ni] = __builtin_amdgcn_mfma_f32_16x16x32_bf16(af[mi], bfr[ni], acc[mi][ni], 0, 0, 0);
        }
        __syncthreads();
        if (t + 2 < 12) stage(t + 2, cur);
    }

    const int r4 = (lane >> 4) * 4;
#pragma unroll
    for (int mi = 0; mi < 2; mi++)
#pragma unroll
        for (int r = 0; r < 4; r++) {
            int row = m0 + wm * 32 + mi * 16 + r4 + r;
            int cl = text[row * NSTEP + step];
#pragma unroll
            for (int ni = 0; ni < 2; ni++) {
                int col = n0 + wn * 32 + ni * 16 + (lane & 15);
                float v = acc[mi][ni][r] + b_ih[col] + b_hh[col]
                        + w_ih[(size_t)col * 294 + 256 + cl];
                gates[(size_t)row * 1024 + col] = v;
            }
        }
}

// ---------------------------------------------------------------------------
// attn_full: LSTM(s-1) [+ hseq write] + hp + scores + softmax + ctx + A2.
// 1024 blocks x 256 threads, one row/block, XCD-pinned.  (proven round 14)
// ---------------------------------------------------------------------------
__global__ __launch_bounds__(256) void attn_full(
    const float* __restrict__ gates,
    const ushort_t* __restrict__ w2hb, const float* __restrict__ b_h2h,
    const float* __restrict__ w_score,
    const ushort_t* __restrict__ encb, const ushort_t* __restrict__ Hb,
    float* __restrict__ c, ushort_t* __restrict__ A2,
    float* __restrict__ hseq, int step)
{
    __shared__ float hsh[HD];
    __shared__ float hpsh[HD];
    __shared__ float wssh[HD];
    __shared__ float esh[TT];
    __shared__ float psh[8][HD + 1];

    const int tid = threadIdx.x;
    const int bid = blockIdx.x;
    const int b = (bid & 7) * 128 + (bid >> 3);

    wssh[tid] = w_score[tid];

    if (step > 0) {
        // LSTM(step-1): one element per thread
        const float* g = &gates[(size_t)b * 1024];
        float gi = g[tid];
        float gf = g[256 + tid];
        float gg = g[512 + tid];
        float go = g[768 + tid];
        float cv = c[(size_t)b * HD + tid];
        float cn = fast_sig(gf) * cv + fast_sig(gi) * fast_tanh(gg);
        float hn = fast_sig(go) * fast_tanh(cn);
        c[(size_t)b * HD + tid] = cn;
        hsh[tid] = hn;
        hseq[((size_t)(step - 1) * NB + b) * HD + tid] = hn;
        if (step < NSTEP) {
            unsigned short hi_ = f2bf(hn);
            A2[(size_t)b * 1024 + 256 + tid] = hi_;
            A2[(size_t)b * 1024 + 768 + tid] = f2bf(hn - bf2f(hi_));
        }
        __syncthreads();
    } else {
        // step 0: h = c = 0
        hsh[tid] = 0.f;
        c[(size_t)b * HD + tid] = 0.f;
        A2[(size_t)b * 1024 + 256 + tid] = 0;
        A2[(size_t)b * 1024 + 768 + tid] = 0;
        __syncthreads();
    }
    if (step >= NSTEP) return;

    // hp[j] = dot(w2hb[j], h) + b_h2h[j], j = tid  (hsh reads broadcast)
    {
        float a = 0.f;
        const ushort_t* wr = &w2hb[(size_t)tid * HD];
#pragma unroll 4
        for (int d = 0; d < HD; d += 8) {
            us8 wv = *(const us8*)&wr[d];
#pragma unroll
            for (int k = 0; k < 8; k++)
                a += bf2f(wv[k]) * hsh[d + k];
        }
        hpsh[tid] = a + b_h2h[tid];
    }
    __syncthreads();

    // scores: 8 threads per t, 32 d each (bf16 Hb)
    {
        int t = tid >> 3, sl = tid & 7;
        const ushort_t* hr = &Hb[((size_t)b * TT + t) * HD];
        float e = 0.f;
#pragma unroll
        for (int jj = 0; jj < 4; jj++) {
            int d0 = sl * 8 + jj * 64;
            us8 hv = *(const us8*)&hr[d0];
#pragma unroll
            for (int k = 0; k < 8; k++) {
                int d = d0 + k;
                e += wssh[d] * fast_tanh(bf2f(hv[k]) + hpsh[d]);
            }
        }
        e += __shfl_xor(e, 4);
        e += __shfl_xor(e, 2);
        e += __shfl_xor(e, 1);
        if (sl == 0) esh[t] = e;
    }
    __syncthreads();

    // softmax over 32 t
    if (tid < 32) {
        float v = esh[tid];
        float m = v;
#pragma unroll
        for (int o = 16; o > 0; o >>= 1) m = fmaxf(m, __shfl_xor(m, o));
        float p = __expf(v - m);
        float ssum = p;
#pragma unroll
        for (int o = 16; o > 0; o >>= 1) ssum += __shfl_xor(ssum, o);
        esh[tid] = p * __builtin_amdgcn_rcpf(ssum);
    }
    __syncthreads();

    // context from bf16 encb: group g=tid>>5 covers t in [4g,4g+4), 8 d/thread
    {
        int g = tid >> 5, l = tid & 31;
        float pp[8] = {0.f, 0.f, 0.f, 0.f, 0.f, 0.f, 0.f, 0.f};
#pragma unroll
        for (int tt = 0; tt < 4; tt++) {
            int t = g * 4 + tt;
            float a = esh[t];
            us8 ev = *(const us8*)&encb[((size_t)b * TT + t) * DIN + l * 8];
#pragma unroll
            for (int k = 0; k < 8; k++)
                pp[k] += a * bf2f(ev[k]);
        }
#pragma unroll
        for (int k = 0; k < 8; k++)
            psh[g][l * 8 + k] = pp[k];
    }
    __syncthreads();
    {
        float a = 0.f;
#pragma unroll
        for (int g = 0; g < 8; g++)
            a += psh[g][tid];
        unsigned short hi_ = f2bf(a);
        A2[(size_t)b * 1024 + tid] = hi_;
        A2[(size_t)b * 1024 + 512 + tid] = f2bf(a - bf2f(hi_));
    }
}

// ---------------------------------------------------------------------------
// probs_final: probs[b][s][j] = hseq[s][b] . w_gen[j] + b_gen[j]
// 2048 blocks: block = b*2+half handles 13 steps of row b.
// w_gen staged in LDS stride-257 ((j+d)%32 banks, <=2-way = free) so the
// dot loop is LDS-only — fixes round-14's 119 us L2-scatter disaster.
// ---------------------------------------------------------------------------
#define SPH 13   // steps per half
__global__ __launch_bounds__(256) void probs_final(
    const float* __restrict__ hseq, const float* __restrict__ w_gen,
    const float* __restrict__ b_gen, float* __restrict__ probs)
{
    __shared__ float wg[NC * 257];    // 39.0 KB
    __shared__ float hsh[SPH * 257];  // 13.4 KB  (52.4 KB total)

    const int tid = threadIdx.x;
    const int b = blockIdx.x >> 1;
    const int half = blockIdx.x & 1;
    const int s0 = half * SPH;

    for (int i = tid; i < NC * HD; i += 256) {
        int j = i >> 8, d = i & 255;
        wg[j * 257 + d] = w_gen[i];
    }
    for (int i = tid; i < SPH * HD; i += 256) {
        int s = i >> 8, d = i & 255;
        hsh[s * 257 + d] = hseq[((size_t)(s0 + s) * NB + b) * HD + d];
    }
    __syncthreads();

    for (int i = tid; i < SPH * NC; i += 256) {
        int s = i / NC, j = i - s * NC;
        const float* wv = &wg[j * 257];
        const float* hv = &hsh[s * 257];
        float a = b_gen[j];
#pragma unroll 8
        for (int d = 0; d < HD; d++)
            a += wv[d] * hv[d];
        probs[((size_t)b * NSTEP + s0 + s) * NC + j] = a;
    }
}

// ---------------------------------------------------------------------------
extern "C" void kernel_launch(void* const* d_in, const int* in_sizes, int n_in,
                              void* d_out, int out_size, void* d_ws, size_t ws_size,
                              hipStream_t stream)
{
    const float* enc     = (const float*)d_in[0];
    const int*   text    = (const int*)d_in[1];
    const float* w_i2h   = (const float*)d_in[4];
    const float* w_h2h   = (const float*)d_in[5];
    const float* b_h2h   = (const float*)d_in[6];
    const float* w_score = (const float*)d_in[7];
    const float* w_ih    = (const float*)d_in[8];
    const float* w_hh    = (const float*)d_in[9];
    const float* b_ih    = (const float*)d_in[10];
    const float* b_hh    = (const float*)d_in[11];
    const float* w_gen   = (const float*)d_in[12];
    const float* b_gen   = (const float*)d_in[13];
    float* out = (float*)d_out;

    const size_t MB = 1024 * 1024;
    char* ws = (char*)d_ws;
    ushort_t* Hb    = (ushort_t*)ws;                          // 16 MB  [0,16)
    ushort_t* B2g   = (ushort_t*)(ws + 16 * MB);              // 3 MB   [16,19)
    ushort_t* B2i   = (ushort_t*)(ws + 19 * MB);              // 384 KB
    ushort_t* w2hb  = (ushort_t*)(ws + 19 * MB + 512 * 1024); // 128 KB
    float*    cbuf  = (float*)(ws + 20 * MB);                 // 1 MB   [20,21)
    ushort_t* A2    = (ushort_t*)(ws + 21 * MB);              // 2 MB   [21,23)
    float*    gates = (float*)(ws + 23 * MB);                 // 4 MB   [23,27)
    ushort_t* encA2 = (ushort_t*)(ws + 27 * MB);              // 32 MB  [27,59)
    float*    hseq  = (float*)(ws + 27 * MB);                 // 26 MB, overlays encA2 (dead after hproj)
    ushort_t* encb  = (ushort_t*)(ws + 59 * MB);              // 16 MB  [59,75)

    prep_all<<<3584, 256, 0, stream>>>(w_ih, w_hh, w_i2h, w_h2h, enc,
                                       B2g, B2i, w2hb, encA2, encb);
    hproj_pipe<<<dim3(512, 4), 256, 0, stream>>>(encA2, B2i, Hb);

    for (int s = 0; s < NSTEP; s++) {
        attn_full<<<1024, 256, 0, stream>>>(gates, w2hb, b_h2h, w_score,
                                            encb, Hb, cbuf, A2, hseq, s);
        gates_pipe<<<256, 256, 0, stream>>>(A2, B2g, b_ih, b_hh,
                                            w_ih, text, s, gates);
    }
    // final LSTM (writes hseq[25])
    attn_full<<<1024, 256, 0, stream>>>(gates, w2hb, b_h2h, w_score,
                                        encb, Hb, cbuf, A2, hseq, NSTEP);
    probs_final<<<2048, 256, 0, stream>>>(hseq, w_gen, b_gen, out);
}

// Round 16
// 1022.961 us; speedup vs baseline: 2.5110x; 1.0207x over previous
//
#include <hip/hip_runtime.h>

#define NB 1024   // batch
#define TT 32     // encoder length
#define DIN 256   // input dim
#define HD 256    // hidden dim
#define NC 38     // classes
#define NSTEP 26  // decode steps

typedef unsigned short ushort_t;
typedef __attribute__((ext_vector_type(8))) short bf16x8;
typedef __attribute__((ext_vector_type(8))) unsigned short us8;
typedef __attribute__((ext_vector_type(4))) float f32x4;

#define GLOAD_LDS16(g, l) \
  __builtin_amdgcn_global_load_lds((const __attribute__((address_space(1))) unsigned int*)(g), \
                                   (__attribute__((address_space(3))) unsigned int*)(l), 16, 0, 0)

__device__ __forceinline__ unsigned short f2bf(float x) {
    union { float f; unsigned u; } v; v.f = x;
    unsigned r = v.u + 0x7fff + ((v.u >> 16) & 1);   // RNE
    return (unsigned short)(r >> 16);
}
__device__ __forceinline__ float bf2f(unsigned short h) {
    union { unsigned u; float f; } v; v.u = ((unsigned)h) << 16;
    return v.f;
}
__device__ __forceinline__ float fast_tanh(float x) {
    float xc = fminf(fmaxf(x, -15.f), 15.f);
    float z = __expf(2.f * xc);
    return (z - 1.f) * __builtin_amdgcn_rcpf(z + 1.f);
}
__device__ __forceinline__ float fast_sig(float x) {
    return __builtin_amdgcn_rcpf(1.f + __expf(-x));
}

// ---------------------------------------------------------------------------
// prep_all: 3904 blocks.
//   [0,1024):    B2g row j (PERMUTED: jorig = (j&3)*256 + (j>>2)) [hi|lo|hi]
//   [1024,1280): B2i row bid-1024      [hi256|lo256|hi256] of w_i2h
//   [1280,1536): w2hb row bid-1280     bf16 w_h2h
//   [1536,3584): encA2 + encb, 16 rows each
//   [3584,3648): w_genP row j (rows >=38 zero) [hi|lo|hi]
//   [3648,3904): zero 4 MB region {c, h, A2}
// ---------------------------------------------------------------------------
__global__ __launch_bounds__(256) void prep_all(
    const float* __restrict__ w_ih, const float* __restrict__ w_hh,
    const float* __restrict__ w_i2h, const float* __restrict__ w_h2h,
    const float* __restrict__ enc, const float* __restrict__ w_gen,
    ushort_t* __restrict__ B2g, ushort_t* __restrict__ B2i,
    ushort_t* __restrict__ w2hb, ushort_t* __restrict__ encA2,
    ushort_t* __restrict__ encb, ushort_t* __restrict__ w_genP,
    float* __restrict__ zbase)
{
    const int bid = blockIdx.x, tid = threadIdx.x;
    if (bid < 1024) {
        int j = bid;
        int jorig = ((j & 3) << 8) + (j >> 2);   // gate-interleaved cols
        for (int k = tid; k < 512; k += 256) {
            float x = (k < 256) ? w_ih[(size_t)jorig * 294 + k]
                                : w_hh[(size_t)jorig * 256 + (k - 256)];
            unsigned short hi = f2bf(x);
            unsigned short lo = f2bf(x - bf2f(hi));
            size_t r = (size_t)j * 1536;
            B2g[r + k] = hi; B2g[r + 512 + k] = lo; B2g[r + 1024 + k] = hi;
        }
    } else if (bid < 1280) {
        int n = bid - 1024;
        float x = w_i2h[(size_t)n * 256 + tid];
        unsigned short hi = f2bf(x);
        unsigned short lo = f2bf(x - bf2f(hi));
        size_t r = (size_t)n * 768;
        B2i[r + tid] = hi; B2i[r + 256 + tid] = lo; B2i[r + 512 + tid] = hi;
    } else if (bid < 1536) {
        int j = bid - 1280;
        w2hb[(size_t)j * 256 + tid] = f2bf(w_h2h[(size_t)j * 256 + tid]);
    } else if (bid < 3584) {
        int base = (bid - 1536) * 16;
#pragma unroll
        for (int rr = 0; rr < 16; rr++) {
            size_t row = base + rr;
            float x = enc[row * 256 + tid];
            unsigned short hi = f2bf(x);
            unsigned short lo = f2bf(x - bf2f(hi));
            encA2[row * 512 + tid] = hi;
            encA2[row * 512 + 256 + tid] = lo;
            encb[row * 256 + tid] = hi;
        }
    } else if (bid < 3648) {
        int j = bid - 3584;
        float x = (j < NC) ? w_gen[(size_t)j * 256 + tid] : 0.f;
        unsigned short hi = f2bf(x);
        unsigned short lo = f2bf(x - bf2f(hi));
        size_t r = (size_t)j * 768;
        w_genP[r + tid] = hi; w_genP[r + 256 + tid] = lo; w_genP[r + 512 + tid] = hi;
    } else {
        float* z = zbase + (size_t)(bid - 3648) * 4096;
        const float4 f4z = make_float4(0.f, 0.f, 0.f, 0.f);
#pragma unroll
        for (int k = 0; k < 4; k++)
            *(float4*)&z[(tid + k * 256) * 4] = f4z;
    }
}

// ---------------------------------------------------------------------------
// hproj_pipe: Hb[m][n] = bf16( sum_k enc[m][k]*w_i2h[n][k] )   (proven)
// ---------------------------------------------------------------------------
__global__ __launch_bounds__(256) void hproj_pipe(
    const ushort_t* __restrict__ encA2, const ushort_t* __restrict__ B2i,
    ushort_t* __restrict__ Hb)
{
    __shared__ ushort_t lA[2][64 * 128];
    __shared__ ushort_t lB[2][64 * 128];

    const int tid = threadIdx.x;
    const int lane = tid & 63, wid = tid >> 6;
    const int wm = wid >> 1, wn = wid & 1;
    const int m0 = blockIdx.x * 64, n0 = blockIdx.y * 64;

    f32x4 acc[2][2];
    const f32x4 fz = {0.f, 0.f, 0.f, 0.f};
    acc[0][0] = fz; acc[0][1] = fz; acc[1][0] = fz; acc[1][1] = fz;

    auto stage = [&](int t, int buf) {
#pragma unroll
        for (int i = 0; i < 4; i++) {
            int cpos = tid + i * 256;
            int m = cpos >> 4, p = cpos & 15;
            int g = p ^ (m & 7);
            int vk = t * 128 + g * 8;
            int acol = (vk < 256) ? vk : vk - 256;
            GLOAD_LDS16(&encA2[(size_t)(m0 + m) * 512 + acol], &lA[buf][cpos * 8]);
        }
#pragma unroll
        for (int i = 0; i < 4; i++) {
            int cpos = tid + i * 256;
            int n = cpos >> 4, p = cpos & 15;
            int g = p ^ (n & 7);
            GLOAD_LDS16(&B2i[(size_t)(n0 + n) * 768 + t * 128 + g * 8], &lB[buf][cpos * 8]);
        }
    };

    stage(0, 0);
    stage(1, 1);

    for (int t = 0; t < 6; t++) {
        int cur = t & 1;
        if (t < 5) asm volatile("s_waitcnt vmcnt(8)" ::: "memory");
        else       asm volatile("s_waitcnt vmcnt(0)" ::: "memory");
        __syncthreads();
#pragma unroll
        for (int kk = 0; kk < 4; kk++) {
            int g = kk * 4 + (lane >> 4);
            bf16x8 af[2], bfr[2];
#pragma unroll
            for (int mi = 0; mi < 2; mi++) {
                int m = wm * 32 + mi * 16 + (lane & 15);
                af[mi] = *(const bf16x8*)&lA[cur][m * 128 + ((g ^ (m & 7)) << 3)];
            }
#pragma unroll
            for (int ni = 0; ni < 2; ni++) {
                int n = wn * 32 + ni * 16 + (lane & 15);
                bfr[ni] = *(const bf16x8*)&lB[cur][n * 128 + ((g ^ (n & 7)) << 3)];
            }
#pragma unroll
            for (int mi = 0; mi < 2; mi++)
#pragma unroll
                for (int ni = 0; ni < 2; ni++)
                    acc[mi][ni] = __builtin_amdgcn_mfma_f32_16x16x32_bf16(af[mi], bfr[ni], acc[mi][ni], 0, 0, 0);
        }
        __syncthreads();
        if (t + 2 < 6) stage(t + 2, cur);
    }

    const int r4 = (lane >> 4) * 4;
#pragma unroll
    for (int mi = 0; mi < 2; mi++)
#pragma unroll
        for (int r = 0; r < 4; r++) {
            size_t row = m0 + wm * 32 + mi * 16 + r4 + r;
#pragma unroll
            for (int ni = 0; ni < 2; ni++) {
                int col = n0 + wn * 32 + ni * 16 + (lane & 15);
                Hb[row * 256 + col] = f2bf(acc[mi][ni][r]);
            }
        }
}

// ---------------------------------------------------------------------------
// gates_lstm: gates GEMM (gate-interleaved cols) + fused LSTM epilogue.
// 256 blocks, XCD-pinned n-panels.  n-panel covers hh [n0>>2, n0>>2+16).
// Writes c, h (fp32), A2 h-parts (bf16 hi/lo), hseq2 (bf16 hi/lo).
// The 4 MB gates buffer is GONE.
// ---------------------------------------------------------------------------
__global__ __launch_bounds__(256) void gates_lstm(
    const ushort_t* __restrict__ A2in, const ushort_t* __restrict__ B2,
    const float* __restrict__ b_ih, const float* __restrict__ b_hh,
    const float* __restrict__ w_ih, const int* __restrict__ text,
    float* __restrict__ c, float* __restrict__ h,
    ushort_t* __restrict__ A2out, ushort_t* __restrict__ hseq2,
    int step)
{
    __shared__ ushort_t lA[2][64 * 128];
    __shared__ ushort_t lB[2][64 * 128];

    const int tid = threadIdx.x;
    const int bid = blockIdx.x;
    const int xcd = bid & 7, j = bid >> 3;
    const int m0 = (j >> 1) * 64;
    const int n0 = (xcd * 2 + (j & 1)) * 64;
    const int lane = tid & 63, wid = tid >> 6;
    const int wm = wid >> 1, wn = wid & 1;

    f32x4 acc[2][2];
    const f32x4 fz = {0.f, 0.f, 0.f, 0.f};
    acc[0][0] = fz; acc[0][1] = fz; acc[1][0] = fz; acc[1][1] = fz;

    auto stage = [&](int t, int buf) {
#pragma unroll
        for (int i = 0; i < 4; i++) {
            int cpos = tid + i * 256;
            int m = cpos >> 4, p = cpos & 15;
            int g = p ^ (m & 7);
            int vk = t * 128 + g * 8;
            int acol = (vk < 512) ? vk : vk - 512;
            GLOAD_LDS16(&A2in[(size_t)(m0 + m) * 1024 + acol], &lA[buf][cpos * 8]);
        }
#pragma unroll
        for (int i = 0; i < 4; i++) {
            int cpos = tid + i * 256;
            int n = cpos >> 4, p = cpos & 15;
            int g = p ^ (n & 7);
            GLOAD_LDS16(&B2[(size_t)(n0 + n) * 1536 + t * 128 + g * 8], &lB[buf][cpos * 8]);
        }
    };

    stage(0, 0);
    stage(1, 1);

    for (int t = 0; t < 12; t++) {
        int cur = t & 1;
        if (t < 11) asm volatile("s_waitcnt vmcnt(8)" ::: "memory");
        else        asm volatile("s_waitcnt vmcnt(0)" ::: "memory");
        __syncthreads();
#pragma unroll
        for (int kk = 0; kk < 4; kk++) {
            int g = kk * 4 + (lane >> 4);
            bf16x8 af[2], bfr[2];
#pragma unroll
            for (int mi = 0; mi < 2; mi++) {
                int m = wm * 32 + mi * 16 + (lane & 15);
                af[mi] = *(const bf16x8*)&lA[cur][m * 128 + ((g ^ (m & 7)) << 3)];
            }
#pragma unroll
            for (int ni = 0; ni < 2; ni++) {
                int n = wn * 32 + ni * 16 + (lane & 15);
                bfr[ni] = *(const bf16x8*)&lB[cur][n * 128 + ((g ^ (n & 7)) << 3)];
            }
#pragma unroll
            for (int mi = 0; mi < 2; mi++)
#pragma unroll
                for (int ni = 0; ni < 2; ni++)
                    acc[mi][ni] = __builtin_amdgcn_mfma_f32_16x16x32_bf16(af[mi], bfr[ni], acc[mi][ni], 0, 0, 0);
        }
        __syncthreads();
        if (t + 2 < 12) stage(t + 2, cur);
    }

    // ---- epilogue 1: gates tile -> LDS (with bias + onehot) ----
    float* ltile = (float*)&lA[0][0];   // 16 KB, safe after final sync
    const int r4 = (lane >> 4) * 4;
#pragma unroll
    for (int ni = 0; ni < 2; ni++) {
        int colg = n0 + wn * 32 + ni * 16 + (lane & 15);
        int jorig = ((colg & 3) << 8) + (colg >> 2);
        float bsum = b_ih[jorig] + b_hh[jorig];
        const float* wcol = &w_ih[(size_t)jorig * 294 + 256];
        int col_l = colg - n0;
#pragma unroll
        for (int mi = 0; mi < 2; mi++)
#pragma unroll
            for (int r = 0; r < 4; r++) {
                int row_l = wm * 32 + mi * 16 + r4 + r;
                int cl = text[(m0 + row_l) * NSTEP + step];
                ltile[row_l * 64 + col_l] = acc[mi][ni][r] + bsum + wcol[cl];
            }
    }
    __syncthreads();

    // ---- epilogue 2: LSTM for 64 rows x 16 hh ----
    const int hh0 = n0 >> 2;
#pragma unroll
    for (int it = 0; it < 4; it++) {
        int idx = tid + it * 256;
        int row_l = idx >> 4, hl = idx & 15;
        int row = m0 + row_l;
        int hh = hh0 + hl;
        float gi = ltile[row_l * 64 + hl * 4 + 0];
        float gf = ltile[row_l * 64 + hl * 4 + 1];
        float gg = ltile[row_l * 64 + hl * 4 + 2];
        float go = ltile[row_l * 64 + hl * 4 + 3];
        float cv = c[(size_t)row * HD + hh];
        float cn = fast_sig(gf) * cv + fast_sig(gi) * fast_tanh(gg);
        float hn = fast_sig(go) * fast_tanh(cn);
        c[(size_t)row * HD + hh] = cn;
        h[(size_t)row * HD + hh] = hn;
        unsigned short hi_ = f2bf(hn);
        unsigned short lo_ = f2bf(hn - bf2f(hi_));
        A2out[(size_t)row * 1024 + 256 + hh] = hi_;
        A2out[(size_t)row * 1024 + 768 + hh] = lo_;
        size_t hr = ((size_t)step * NB + row) * 512;
        hseq2[hr + hh] = hi_;
        hseq2[hr + 256 + hh] = lo_;
    }
}

// ---------------------------------------------------------------------------
// attn_full: hp + scores + softmax + ctx + A2 ctx-parts.  Step-independent
// (h read from global; LSTM moved to gates_lstm).  1024 blocks, XCD-pinned.
// ---------------------------------------------------------------------------
__global__ __launch_bounds__(256) void attn_full(
    const float* __restrict__ h,
    const ushort_t* __restrict__ w2hb, const float* __restrict__ b_h2h,
    const float* __restrict__ w_score,
    const ushort_t* __restrict__ encb, const ushort_t* __restrict__ Hb,
    ushort_t* __restrict__ A2)
{
    __shared__ float hsh[HD];
    __shared__ float hpsh[HD];
    __shared__ float wssh[HD];
    __shared__ float esh[TT];
    __shared__ float psh[8][HD + 1];

    const int tid = threadIdx.x;
    const int bid = blockIdx.x;
    const int b = (bid & 7) * 128 + (bid >> 3);

    wssh[tid] = w_score[tid];
    hsh[tid] = h[(size_t)b * HD + tid];
    __syncthreads();

    // hp[j] = dot(w2hb[j], h) + b_h2h[j], j = tid
    {
        float a = 0.f;
        const ushort_t* wr = &w2hb[(size_t)tid * HD];
#pragma unroll 4
        for (int d = 0; d < HD; d += 8) {
            us8 wv = *(const us8*)&wr[d];
#pragma unroll
            for (int k = 0; k < 8; k++)
                a += bf2f(wv[k]) * hsh[d + k];
        }
        hpsh[tid] = a + b_h2h[tid];
    }
    __syncthreads();

    // scores: 8 threads per t, 32 d each (bf16 Hb)
    {
        int t = tid >> 3, sl = tid & 7;
        const ushort_t* hr = &Hb[((size_t)b * TT + t) * HD];
        float e = 0.f;
#pragma unroll
        for (int jj = 0; jj < 4; jj++) {
            int d0 = sl * 8 + jj * 64;
            us8 hv = *(const us8*)&hr[d0];
#pragma unroll
            for (int k = 0; k < 8; k++) {
                int d = d0 + k;
                e += wssh[d] * fast_tanh(bf2f(hv[k]) + hpsh[d]);
            }
        }
        e += __shfl_xor(e, 4);
        e += __shfl_xor(e, 2);
        e += __shfl_xor(e, 1);
        if (sl == 0) esh[t] = e;
    }
    __syncthreads();

    // softmax over 32 t
    if (tid < 32) {
        float v = esh[tid];
        float m = v;
#pragma unroll
        for (int o = 16; o > 0; o >>= 1) m = fmaxf(m, __shfl_xor(m, o));
        float p = __expf(v - m);
        float ssum = p;
#pragma unroll
        for (int o = 16; o > 0; o >>= 1) ssum += __shfl_xor(ssum, o);
        esh[tid] = p * __builtin_amdgcn_rcpf(ssum);
    }
    __syncthreads();

    // context from bf16 encb
    {
        int g = tid >> 5, l = tid & 31;
        float pp[8] = {0.f, 0.f, 0.f, 0.f, 0.f, 0.f, 0.f, 0.f};
#pragma unroll
        for (int tt = 0; tt < 4; tt++) {
            int t = g * 4 + tt;
            float a = esh[t];
            us8 ev = *(const us8*)&encb[((size_t)b * TT + t) * DIN + l * 8];
#pragma unroll
            for (int k = 0; k < 8; k++)
                pp[k] += a * bf2f(ev[k]);
        }
#pragma unroll
        for (int k = 0; k < 8; k++)
            psh[g][l * 8 + k] = pp[k];
    }
    __syncthreads();
    {
        float a = 0.f;
#pragma unroll
        for (int g = 0; g < 8; g++)
            a += psh[g][tid];
        unsigned short hi_ = f2bf(a);
        A2[(size_t)b * 1024 + tid] = hi_;
        A2[(size_t)b * 1024 + 512 + tid] = f2bf(a - bf2f(hi_));
    }
}

// ---------------------------------------------------------------------------
// probs_mfma: probs = hseq2 @ w_genP.T  (split-bf16, virtual K=768)
// M = 26624 (row = s*1024 + b), N = 64 (cols >= 38 discarded).
// 416 blocks; hproj_pipe skeleton.
// ---------------------------------------------------------------------------
__global__ __launch_bounds__(256) void probs_mfma(
    const ushort_t* __restrict__ hseq2, const ushort_t* __restrict__ w_genP,
    const float* __restrict__ b_gen, float* __restrict__ probs)
{
    __shared__ ushort_t lA[2][64 * 128];
    __shared__ ushort_t lB[2][64 * 128];

    const int tid = threadIdx.x;
    const int lane = tid & 63, wid = tid >> 6;
    const int wm = wid >> 1, wn = wid & 1;
    const int m0 = blockIdx.x * 64;

    f32x4 acc[2][2];
    const f32x4 fz = {0.f, 0.f, 0.f, 0.f};
    acc[0][0] = fz; acc[0][1] = fz; acc[1][0] = fz; acc[1][1] = fz;

    auto stage = [&](int t, int buf) {
#pragma unroll
        for (int i = 0; i < 4; i++) {
            int cpos = tid + i * 256;
            int m = cpos >> 4, p = cpos & 15;
            int g = p ^ (m & 7);
            int vk = t * 128 + g * 8;
            int acol = (vk < 256) ? vk : vk - 256;
            GLOAD_LDS16(&hseq2[(size_t)(m0 + m) * 512 + acol], &lA[buf][cpos * 8]);
        }
#pragma unroll
        for (int i = 0; i < 4; i++) {
            int cpos = tid + i * 256;
            int n = cpos >> 4, p = cpos & 15;
            int g = p ^ (n & 7);
            GLOAD_LDS16(&w_genP[(size_t)n * 768 + t * 128 + g * 8], &lB[buf][cpos * 8]);
        }
    };

    stage(0, 0);
    stage(1, 1);

    for (int t = 0; t < 6; t++) {
        int cur = t & 1;
        if (t < 5) asm volatile("s_waitcnt vmcnt(8)" ::: "memory");
        else       asm volatile("s_waitcnt vmcnt(0)" ::: "memory");
        __syncthreads();
#pragma unroll
        for (int kk = 0; kk < 4; kk++) {
            int g = kk * 4 + (lane >> 4);
            bf16x8 af[2], bfr[2];
#pragma unroll
            for (int mi = 0; mi < 2; mi++) {
                int m = wm * 32 + mi * 16 + (lane & 15);
                af[mi] = *(const bf16x8*)&lA[cur][m * 128 + ((g ^ (m & 7)) << 3)];
            }
#pragma unroll
            for (int ni = 0; ni < 2; ni++) {
                int n = wn * 32 + ni * 16 + (lane & 15);
                bfr[ni] = *(const bf16x8*)&lB[cur][n * 128 + ((g ^ (n & 7)) << 3)];
            }
#pragma unroll
            for (int mi = 0; mi < 2; mi++)
#pragma unroll
                for (int ni = 0; ni < 2; ni++)
                    acc[mi][ni] = __builtin_amdgcn_mfma_f32_16x16x32_bf16(af[mi], bfr[ni], acc[mi][ni], 0, 0, 0);
        }
        __syncthreads();
        if (t + 2 < 6) stage(t + 2, cur);
    }

    const int r4 = (lane >> 4) * 4;
    const int s = blockIdx.x >> 4;
    const int b0 = (blockIdx.x & 15) * 64;
#pragma unroll
    for (int ni = 0; ni < 2; ni++) {
        int col = wn * 32 + ni * 16 + (lane & 15);
        if (col < NC) {
            float bb = b_gen[col];
#pragma unroll
            for (int mi = 0; mi < 2; mi++)
#pragma unroll
                for (int r = 0; r < 4; r++) {
                    int b = b0 + wm * 32 + mi * 16 + r4 + r;
                    probs[((size_t)b * NSTEP + s) * NC + col] = acc[mi][ni][r] + bb;
                }
        }
    }
}

// ---------------------------------------------------------------------------
extern "C" void kernel_launch(void* const* d_in, const int* in_sizes, int n_in,
                              void* d_out, int out_size, void* d_ws, size_t ws_size,
                              hipStream_t stream)
{
    const float* enc     = (const float*)d_in[0];
    const int*   text    = (const int*)d_in[1];
    const float* w_i2h   = (const float*)d_in[4];
    const float* w_h2h   = (const float*)d_in[5];
    const float* b_h2h   = (const float*)d_in[6];
    const float* w_score = (const float*)d_in[7];
    const float* w_ih    = (const float*)d_in[8];
    const float* w_hh    = (const float*)d_in[9];
    const float* b_ih    = (const float*)d_in[10];
    const float* b_hh    = (const float*)d_in[11];
    const float* w_gen   = (const float*)d_in[12];
    const float* b_gen   = (const float*)d_in[13];
    float* out = (float*)d_out;

    const size_t MB = 1024 * 1024;
    char* ws = (char*)d_ws;
    ushort_t* Hb     = (ushort_t*)ws;                          // 16 MB  [0,16)
    ushort_t* B2g    = (ushort_t*)(ws + 16 * MB);              // 3 MB   [16,19)
    ushort_t* B2i    = (ushort_t*)(ws + 19 * MB);              // 384 KB
    ushort_t* w2hb   = (ushort_t*)(ws + 19 * MB + 512 * 1024); // 128 KB
    ushort_t* w_genP = (ushort_t*)(ws + 19 * MB + 768 * 1024); // 96 KB
    float*    cbuf   = (float*)(ws + 20 * MB);                 // 1 MB   [20,21)
    float*    hbuf   = (float*)(ws + 21 * MB);                 // 1 MB   [21,22)
    ushort_t* A2     = (ushort_t*)(ws + 22 * MB);              // 2 MB   [22,24)
    ushort_t* encA2  = (ushort_t*)(ws + 27 * MB);              // 32 MB  [27,59)
    ushort_t* hseq2  = (ushort_t*)(ws + 27 * MB);              // 26 MB, overlays encA2
    ushort_t* encb   = (ushort_t*)(ws + 59 * MB);              // 16 MB  [59,75)
    float*    zbase  = cbuf;                                   // zero {c,h,A2} = 4 MB

    prep_all<<<3904, 256, 0, stream>>>(w_ih, w_hh, w_i2h, w_h2h, enc, w_gen,
                                       B2g, B2i, w2hb, encA2, encb, w_genP, zbase);
    hproj_pipe<<<dim3(512, 4), 256, 0, stream>>>(encA2, B2i, Hb);

    for (int s = 0; s < NSTEP; s++) {
        attn_full<<<1024, 256, 0, stream>>>(hbuf, w2hb, b_h2h, w_score,
                                            encb, Hb, A2);
        gates_lstm<<<256, 256, 0, stream>>>(A2, B2g, b_ih, b_hh, w_ih, text,
                                            cbuf, hbuf, A2, hseq2, s);
    }
    probs_mfma<<<416, 256, 0, stream>>>(hseq2, w_genP, b_gen, out);
}

// Round 17
// 889.957 us; speedup vs baseline: 2.8863x; 1.1495x over previous
//
#include <hip/hip_runtime.h>

#define NB 1024   // batch
#define TT 32     // encoder length
#define DIN 256   // input dim
#define HD 256    // hidden dim
#define NC 38     // classes
#define NSTEP 26  // decode steps

typedef unsigned short ushort_t;
typedef __attribute__((ext_vector_type(8))) short bf16x8;
typedef __attribute__((ext_vector_type(8))) unsigned short us8;
typedef __attribute__((ext_vector_type(4))) float f32x4;

#define GLOAD_LDS16(g, l) \
  __builtin_amdgcn_global_load_lds((const __attribute__((address_space(1))) unsigned int*)(g), \
                                   (__attribute__((address_space(3))) unsigned int*)(l), 16, 0, 0)

__device__ __forceinline__ unsigned short f2bf(float x) {
    union { float f; unsigned u; } v; v.f = x;
    unsigned r = v.u + 0x7fff + ((v.u >> 16) & 1);   // RNE
    return (unsigned short)(r >> 16);
}
__device__ __forceinline__ float bf2f(unsigned short h) {
    union { unsigned u; float f; } v; v.u = ((unsigned)h) << 16;
    return v.f;
}
__device__ __forceinline__ float fast_tanh(float x) {
    float xc = fminf(fmaxf(x, -15.f), 15.f);
    float z = __expf(2.f * xc);
    return (z - 1.f) * __builtin_amdgcn_rcpf(z + 1.f);
}
__device__ __forceinline__ float fast_sig(float x) {
    return __builtin_amdgcn_rcpf(1.f + __expf(-x));
}

// ---------------------------------------------------------------------------
// prep_all: 3904 blocks.  (verbatim round 16, proven)
// ---------------------------------------------------------------------------
__global__ __launch_bounds__(256) void prep_all(
    const float* __restrict__ w_ih, const float* __restrict__ w_hh,
    const float* __restrict__ w_i2h, const float* __restrict__ w_h2h,
    const float* __restrict__ enc, const float* __restrict__ w_gen,
    ushort_t* __restrict__ B2g, ushort_t* __restrict__ B2i,
    ushort_t* __restrict__ w2hb, ushort_t* __restrict__ encA2,
    ushort_t* __restrict__ encb, ushort_t* __restrict__ w_genP,
    float* __restrict__ zbase)
{
    const int bid = blockIdx.x, tid = threadIdx.x;
    if (bid < 1024) {
        int j = bid;
        int jorig = ((j & 3) << 8) + (j >> 2);   // gate-interleaved cols
        for (int k = tid; k < 512; k += 256) {
            float x = (k < 256) ? w_ih[(size_t)jorig * 294 + k]
                                : w_hh[(size_t)jorig * 256 + (k - 256)];
            unsigned short hi = f2bf(x);
            unsigned short lo = f2bf(x - bf2f(hi));
            size_t r = (size_t)j * 1536;
            B2g[r + k] = hi; B2g[r + 512 + k] = lo; B2g[r + 1024 + k] = hi;
        }
    } else if (bid < 1280) {
        int n = bid - 1024;
        float x = w_i2h[(size_t)n * 256 + tid];
        unsigned short hi = f2bf(x);
        unsigned short lo = f2bf(x - bf2f(hi));
        size_t r = (size_t)n * 768;
        B2i[r + tid] = hi; B2i[r + 256 + tid] = lo; B2i[r + 512 + tid] = hi;
    } else if (bid < 1536) {
        int j = bid - 1280;
        w2hb[(size_t)j * 256 + tid] = f2bf(w_h2h[(size_t)j * 256 + tid]);
    } else if (bid < 3584) {
        int base = (bid - 1536) * 16;
#pragma unroll
        for (int rr = 0; rr < 16; rr++) {
            size_t row = base + rr;
            float x = enc[row * 256 + tid];
            unsigned short hi = f2bf(x);
            unsigned short lo = f2bf(x - bf2f(hi));
            encA2[row * 512 + tid] = hi;
            encA2[row * 512 + 256 + tid] = lo;
            encb[row * 256 + tid] = hi;
        }
    } else if (bid < 3648) {
        int j = bid - 3584;
        float x = (j < NC) ? w_gen[(size_t)j * 256 + tid] : 0.f;
        unsigned short hi = f2bf(x);
        unsigned short lo = f2bf(x - bf2f(hi));
        size_t r = (size_t)j * 768;
        w_genP[r + tid] = hi; w_genP[r + 256 + tid] = lo; w_genP[r + 512 + tid] = hi;
    } else {
        float* z = zbase + (size_t)(bid - 3648) * 4096;
        const float4 f4z = make_float4(0.f, 0.f, 0.f, 0.f);
#pragma unroll
        for (int k = 0; k < 4; k++)
            *(float4*)&z[(tid + k * 256) * 4] = f4z;
    }
}

// ---------------------------------------------------------------------------
// hproj_pipe: Hb[m][n] = bf16( sum_k enc[m][k]*w_i2h[n][k] )   (proven)
// ---------------------------------------------------------------------------
__global__ __launch_bounds__(256) void hproj_pipe(
    const ushort_t* __restrict__ encA2, const ushort_t* __restrict__ B2i,
    ushort_t* __restrict__ Hb)
{
    __shared__ ushort_t lA[2][64 * 128];
    __shared__ ushort_t lB[2][64 * 128];

    const int tid = threadIdx.x;
    const int lane = tid & 63, wid = tid >> 6;
    const int wm = wid >> 1, wn = wid & 1;
    const int m0 = blockIdx.x * 64, n0 = blockIdx.y * 64;

    f32x4 acc[2][2];
    const f32x4 fz = {0.f, 0.f, 0.f, 0.f};
    acc[0][0] = fz; acc[0][1] = fz; acc[1][0] = fz; acc[1][1] = fz;

    auto stage = [&](int t, int buf) {
#pragma unroll
        for (int i = 0; i < 4; i++) {
            int cpos = tid + i * 256;
            int m = cpos >> 4, p = cpos & 15;
            int g = p ^ (m & 7);
            int vk = t * 128 + g * 8;
            int acol = (vk < 256) ? vk : vk - 256;
            GLOAD_LDS16(&encA2[(size_t)(m0 + m) * 512 + acol], &lA[buf][cpos * 8]);
        }
#pragma unroll
        for (int i = 0; i < 4; i++) {
            int cpos = tid + i * 256;
            int n = cpos >> 4, p = cpos & 15;
            int g = p ^ (n & 7);
            GLOAD_LDS16(&B2i[(size_t)(n0 + n) * 768 + t * 128 + g * 8], &lB[buf][cpos * 8]);
        }
    };

    stage(0, 0);
    stage(1, 1);

    for (int t = 0; t < 6; t++) {
        int cur = t & 1;
        if (t < 5) asm volatile("s_waitcnt vmcnt(8)" ::: "memory");
        else       asm volatile("s_waitcnt vmcnt(0)" ::: "memory");
        __syncthreads();
#pragma unroll
        for (int kk = 0; kk < 4; kk++) {
            int g = kk * 4 + (lane >> 4);
            bf16x8 af[2], bfr[2];
#pragma unroll
            for (int mi = 0; mi < 2; mi++) {
                int m = wm * 32 + mi * 16 + (lane & 15);
                af[mi] = *(const bf16x8*)&lA[cur][m * 128 + ((g ^ (m & 7)) << 3)];
            }
#pragma unroll
            for (int ni = 0; ni < 2; ni++) {
                int n = wn * 32 + ni * 16 + (lane & 15);
                bfr[ni] = *(const bf16x8*)&lB[cur][n * 128 + ((g ^ (n & 7)) << 3)];
            }
#pragma unroll
            for (int mi = 0; mi < 2; mi++)
#pragma unroll
                for (int ni = 0; ni < 2; ni++)
                    acc[mi][ni] = __builtin_amdgcn_mfma_f32_16x16x32_bf16(af[mi], bfr[ni], acc[mi][ni], 0, 0, 0);
        }
        __syncthreads();
        if (t + 2 < 6) stage(t + 2, cur);
    }

    const int r4 = (lane >> 4) * 4;
#pragma unroll
    for (int mi = 0; mi < 2; mi++)
#pragma unroll
        for (int r = 0; r < 4; r++) {
            size_t row = m0 + wm * 32 + mi * 16 + r4 + r;
#pragma unroll
            for (int ni = 0; ni < 2; ni++) {
                int col = n0 + wn * 32 + ni * 16 + (lane & 15);
                Hb[row * 256 + col] = f2bf(acc[mi][ni][r]);
            }
        }
}

// ---------------------------------------------------------------------------
// gates_lstm: gates GEMM (gate-interleaved cols) + fused LSTM epilogue.
// (verbatim round 16, proven)
// ---------------------------------------------------------------------------
__global__ __launch_bounds__(256) void gates_lstm(
    const ushort_t* __restrict__ A2in, const ushort_t* __restrict__ B2,
    const float* __restrict__ b_ih, const float* __restrict__ b_hh,
    const float* __restrict__ w_ih, const int* __restrict__ text,
    float* __restrict__ c, float* __restrict__ h,
    ushort_t* __restrict__ A2out, ushort_t* __restrict__ hseq2,
    int step)
{
    __shared__ ushort_t lA[2][64 * 128];
    __shared__ ushort_t lB[2][64 * 128];

    const int tid = threadIdx.x;
    const int bid = blockIdx.x;
    const int xcd = bid & 7, j = bid >> 3;
    const int m0 = (j >> 1) * 64;
    const int n0 = (xcd * 2 + (j & 1)) * 64;
    const int lane = tid & 63, wid = tid >> 6;
    const int wm = wid >> 1, wn = wid & 1;

    f32x4 acc[2][2];
    const f32x4 fz = {0.f, 0.f, 0.f, 0.f};
    acc[0][0] = fz; acc[0][1] = fz; acc[1][0] = fz; acc[1][1] = fz;

    auto stage = [&](int t, int buf) {
#pragma unroll
        for (int i = 0; i < 4; i++) {
            int cpos = tid + i * 256;
            int m = cpos >> 4, p = cpos & 15;
            int g = p ^ (m & 7);
            int vk = t * 128 + g * 8;
            int acol = (vk < 512) ? vk : vk - 512;
            GLOAD_LDS16(&A2in[(size_t)(m0 + m) * 1024 + acol], &lA[buf][cpos * 8]);
        }
#pragma unroll
        for (int i = 0; i < 4; i++) {
            int cpos = tid + i * 256;
            int n = cpos >> 4, p = cpos & 15;
            int g = p ^ (n & 7);
            GLOAD_LDS16(&B2[(size_t)(n0 + n) * 1536 + t * 128 + g * 8], &lB[buf][cpos * 8]);
        }
    };

    stage(0, 0);
    stage(1, 1);

    for (int t = 0; t < 12; t++) {
        int cur = t & 1;
        if (t < 11) asm volatile("s_waitcnt vmcnt(8)" ::: "memory");
        else        asm volatile("s_waitcnt vmcnt(0)" ::: "memory");
        __syncthreads();
#pragma unroll
        for (int kk = 0; kk < 4; kk++) {
            int g = kk * 4 + (lane >> 4);
            bf16x8 af[2], bfr[2];
#pragma unroll
            for (int mi = 0; mi < 2; mi++) {
                int m = wm * 32 + mi * 16 + (lane & 15);
                af[mi] = *(const bf16x8*)&lA[cur][m * 128 + ((g ^ (m & 7)) << 3)];
            }
#pragma unroll
            for (int ni = 0; ni < 2; ni++) {
                int n = wn * 32 + ni * 16 + (lane & 15);
                bfr[ni] = *(const bf16x8*)&lB[cur][n * 128 + ((g ^ (n & 7)) << 3)];
            }
#pragma unroll
            for (int mi = 0; mi < 2; mi++)
#pragma unroll
                for (int ni = 0; ni < 2; ni++)
                    acc[mi][ni] = __builtin_amdgcn_mfma_f32_16x16x32_bf16(af[mi], bfr[ni], acc[mi][ni], 0, 0, 0);
        }
        __syncthreads();
        if (t + 2 < 12) stage(t + 2, cur);
    }

    // ---- epilogue 1: gates tile -> LDS (with bias + onehot) ----
    float* ltile = (float*)&lA[0][0];
    const int r4 = (lane >> 4) * 4;
#pragma unroll
    for (int ni = 0; ni < 2; ni++) {
        int colg = n0 + wn * 32 + ni * 16 + (lane & 15);
        int jorig = ((colg & 3) << 8) + (colg >> 2);
        float bsum = b_ih[jorig] + b_hh[jorig];
        const float* wcol = &w_ih[(size_t)jorig * 294 + 256];
        int col_l = colg - n0;
#pragma unroll
        for (int mi = 0; mi < 2; mi++)
#pragma unroll
            for (int r = 0; r < 4; r++) {
                int row_l = wm * 32 + mi * 16 + r4 + r;
                int cl = text[(m0 + row_l) * NSTEP + step];
                ltile[row_l * 64 + col_l] = acc[mi][ni][r] + bsum + wcol[cl];
            }
    }
    __syncthreads();

    // ---- epilogue 2: LSTM for 64 rows x 16 hh ----
    const int hh0 = n0 >> 2;
#pragma unroll
    for (int it = 0; it < 4; it++) {
        int idx = tid + it * 256;
        int row_l = idx >> 4, hl = idx & 15;
        int row = m0 + row_l;
        int hh = hh0 + hl;
        float gi = ltile[row_l * 64 + hl * 4 + 0];
        float gf = ltile[row_l * 64 + hl * 4 + 1];
        float gg = ltile[row_l * 64 + hl * 4 + 2];
        float go = ltile[row_l * 64 + hl * 4 + 3];
        float cv = c[(size_t)row * HD + hh];
        float cn = fast_sig(gf) * cv + fast_sig(gi) * fast_tanh(gg);
        float hn = fast_sig(go) * fast_tanh(cn);
        c[(size_t)row * HD + hh] = cn;
        h[(size_t)row * HD + hh] = hn;
        unsigned short hi_ = f2bf(hn);
        unsigned short lo_ = f2bf(hn - bf2f(hi_));
        A2out[(size_t)row * 1024 + 256 + hh] = hi_;
        A2out[(size_t)row * 1024 + 768 + hh] = lo_;
        size_t hr = ((size_t)step * NB + row) * 512;
        hseq2[hr + hh] = hi_;
        hseq2[hr + 256 + hh] = lo_;
    }
}

// ---------------------------------------------------------------------------
// attn_full: hp + scores + softmax + ctx + A2 ctx-parts.
// 512 blocks x 256 threads, TWO rows per block (w2hb L2 traffic halved,
// 4-way ILP accumulator chains).  XCD-pinned: rows xcd*128 + 2j, 2j+1.
// ---------------------------------------------------------------------------
__global__ __launch_bounds__(256) void attn_full(
    const float* __restrict__ h,
    const ushort_t* __restrict__ w2hb, const float* __restrict__ b_h2h,
    const float* __restrict__ w_score,
    const ushort_t* __restrict__ encb, const ushort_t* __restrict__ Hb,
    ushort_t* __restrict__ A2)
{
    __shared__ float hsh[2][HD];
    __shared__ float hpsh[2][HD];
    __shared__ float wssh[HD];
    __shared__ float esh[2][TT];
    __shared__ float psh[2][4][HD + 1];

    const int tid = threadIdx.x;
    const int bid = blockIdx.x;
    const int b0 = (bid & 7) * 128 + (bid >> 3) * 2;

    wssh[tid] = w_score[tid];
#pragma unroll
    for (int it = 0; it < 2; it++) {
        int idx = tid + it * 256;
        int row = idx >> 8, d = idx & 255;
        hsh[row][d] = h[(size_t)(b0 + row) * HD + d];
    }
    __syncthreads();

    // hp for both rows; 4 independent accumulator chains
    {
        const ushort_t* wr = &w2hb[(size_t)tid * HD];
        float a0 = 0.f, a1 = 0.f, c0 = 0.f, c1 = 0.f;
#pragma unroll 2
        for (int d = 0; d < HD; d += 16) {
            us8 w0 = *(const us8*)&wr[d];
            us8 w1 = *(const us8*)&wr[d + 8];
#pragma unroll
            for (int k = 0; k < 8; k++) {
                float f0 = bf2f(w0[k]), f1 = bf2f(w1[k]);
                a0 += f0 * hsh[0][d + k];
                c0 += f1 * hsh[0][d + 8 + k];
                a1 += f0 * hsh[1][d + k];
                c1 += f1 * hsh[1][d + 8 + k];
            }
        }
        float bb = b_h2h[tid];
        hpsh[0][tid] = a0 + c0 + bb;
        hpsh[1][tid] = a1 + c1 + bb;
    }
    __syncthreads();

    // scores: 4 threads per (row,t), 64 d each; 2 partial e chains
    {
        int pr = tid >> 2, q = tid & 3;
        int row = pr >> 5, t = pr & 31;
        int d0 = q * 64;
        const ushort_t* hr = &Hb[((size_t)(b0 + row) * TT + t) * HD + d0];
        const float* hp = &hpsh[row][d0];
        const float* wp = &wssh[d0];
        float e0 = 0.f, e1 = 0.f;
#pragma unroll
        for (int jj = 0; jj < 8; jj += 2) {
            us8 hv0 = *(const us8*)&hr[jj * 8];
            us8 hv1 = *(const us8*)&hr[jj * 8 + 8];
#pragma unroll
            for (int k = 0; k < 8; k++) {
                e0 += wp[jj * 8 + k] * fast_tanh(bf2f(hv0[k]) + hp[jj * 8 + k]);
                e1 += wp[jj * 8 + 8 + k] * fast_tanh(bf2f(hv1[k]) + hp[jj * 8 + 8 + k]);
            }
        }
        float e = e0 + e1;
        e += __shfl_xor(e, 1);
        e += __shfl_xor(e, 2);
        if (q == 0) esh[row][t] = e;
    }
    __syncthreads();

    // softmax over 32 t, both rows in wave 0 (lanes 0-31 / 32-63)
    if (tid < 64) {
        int row = tid >> 5, l = tid & 31;
        float v = esh[row][l];
        float m = v;
#pragma unroll
        for (int o = 16; o > 0; o >>= 1) m = fmaxf(m, __shfl_xor(m, o));
        float p = __expf(v - m);
        float ssum = p;
#pragma unroll
        for (int o = 16; o > 0; o >>= 1) ssum += __shfl_xor(ssum, o);
        esh[row][l] = p * __builtin_amdgcn_rcpf(ssum);
    }
    __syncthreads();

    // context: 128 threads/row, 4 groups of 8 t, 8 d per thread
    {
        int row = tid >> 7, rem = tid & 127;
        int g = rem >> 5, l = rem & 31;
        float pp[8] = {0.f, 0.f, 0.f, 0.f, 0.f, 0.f, 0.f, 0.f};
#pragma unroll
        for (int tt = 0; tt < 8; tt++) {
            int t = g * 8 + tt;
            float a = esh[row][t];
            us8 ev = *(const us8*)&encb[((size_t)(b0 + row) * TT + t) * DIN + l * 8];
#pragma unroll
            for (int k = 0; k < 8; k++)
                pp[k] += a * bf2f(ev[k]);
        }
#pragma unroll
        for (int k = 0; k < 8; k++)
            psh[row][g][l * 8 + k] = pp[k];
    }
    __syncthreads();
#pragma unroll
    for (int it = 0; it < 2; it++) {
        int idx = tid + it * 256;
        int row = idx >> 8, d = idx & 255;
        float a = psh[row][0][d] + psh[row][1][d] + psh[row][2][d] + psh[row][3][d];
        unsigned short hi_ = f2bf(a);
        A2[(size_t)(b0 + row) * 1024 + d] = hi_;
        A2[(size_t)(b0 + row) * 1024 + 512 + d] = f2bf(a - bf2f(hi_));
    }
}

// ---------------------------------------------------------------------------
// probs_mfma: probs = hseq2 @ w_genP.T  (split-bf16, virtual K=768)
// (verbatim round 16, proven)
// ---------------------------------------------------------------------------
__global__ __launch_bounds__(256) void probs_mfma(
    const ushort_t* __restrict__ hseq2, const ushort_t* __restrict__ w_genP,
    const float* __restrict__ b_gen, float* __restrict__ probs)
{
    __shared__ ushort_t lA[2][64 * 128];
    __shared__ ushort_t lB[2][64 * 128];

    const int tid = threadIdx.x;
    const int lane = tid & 63, wid = tid >> 6;
    const int wm = wid >> 1, wn = wid & 1;
    const int m0 = blockIdx.x * 64;

    f32x4 acc[2][2];
    const f32x4 fz = {0.f, 0.f, 0.f, 0.f};
    acc[0][0] = fz; acc[0][1] = fz; acc[1][0] = fz; acc[1][1] = fz;

    auto stage = [&](int t, int buf) {
#pragma unroll
        for (int i = 0; i < 4; i++) {
            int cpos = tid + i * 256;
            int m = cpos >> 4, p = cpos & 15;
            int g = p ^ (m & 7);
            int vk = t * 128 + g * 8;
            int acol = (vk < 256) ? vk : vk - 256;
            GLOAD_LDS16(&hseq2[(size_t)(m0 + m) * 512 + acol], &lA[buf][cpos * 8]);
        }
#pragma unroll
        for (int i = 0; i < 4; i++) {
            int cpos = tid + i * 256;
            int n = cpos >> 4, p = cpos & 15;
            int g = p ^ (n & 7);
            GLOAD_LDS16(&w_genP[(size_t)n * 768 + t * 128 + g * 8], &lB[buf][cpos * 8]);
        }
    };

    stage(0, 0);
    stage(1, 1);

    for (int t = 0; t < 6; t++) {
        int cur = t & 1;
        if (t < 5) asm volatile("s_waitcnt vmcnt(8)" ::: "memory");
        else       asm volatile("s_waitcnt vmcnt(0)" ::: "memory");
        __syncthreads();
#pragma unroll
        for (int kk = 0; kk < 4; kk++) {
            int g = kk * 4 + (lane >> 4);
            bf16x8 af[2], bfr[2];
#pragma unroll
            for (int mi = 0; mi < 2; mi++) {
                int m = wm * 32 + mi * 16 + (lane & 15);
                af[mi] = *(const bf16x8*)&lA[cur][m * 128 + ((g ^ (m & 7)) << 3)];
            }
#pragma unroll
            for (int ni = 0; ni < 2; ni++) {
                int n = wn * 32 + ni * 16 + (lane & 15);
                bfr[ni] = *(const bf16x8*)&lB[cur][n * 128 + ((g ^ (n & 7)) << 3)];
            }
#pragma unroll
            for (int mi = 0; mi < 2; mi++)
#pragma unroll
                for (int ni = 0; ni < 2; ni++)
                    acc[mi][ni] = __builtin_amdgcn_mfma_f32_16x16x32_bf16(af[mi], bfr[ni], acc[mi][ni], 0, 0, 0);
        }
        __syncthreads();
        if (t + 2 < 6) stage(t + 2, cur);
    }

    const int r4 = (lane >> 4) * 4;
    const int s = blockIdx.x >> 4;
    const int b0 = (blockIdx.x & 15) * 64;
#pragma unroll
    for (int ni = 0; ni < 2; ni++) {
        int col = wn * 32 + ni * 16 + (lane & 15);
        if (col < NC) {
            float bb = b_gen[col];
#pragma unroll
            for (int mi = 0; mi < 2; mi++)
#pragma unroll
                for (int r = 0; r < 4; r++) {
                    int b = b0 + wm * 32 + mi * 16 + r4 + r;
                    probs[((size_t)b * NSTEP + s) * NC + col] = acc[mi][ni][r] + bb;
                }
        }
    }
}

// ---------------------------------------------------------------------------
extern "C" void kernel_launch(void* const* d_in, const int* in_sizes, int n_in,
                              void* d_out, int out_size, void* d_ws, size_t ws_size,
                              hipStream_t stream)
{
    const float* enc     = (const float*)d_in[0];
    const int*   text    = (const int*)d_in[1];
    const float* w_i2h   = (const float*)d_in[4];
    const float* w_h2h   = (const float*)d_in[5];
    const float* b_h2h   = (const float*)d_in[6];
    const float* w_score = (const float*)d_in[7];
    const float* w_ih    = (const float*)d_in[8];
    const float* w_hh    = (const float*)d_in[9];
    const float* b_ih    = (const float*)d_in[10];
    const float* b_hh    = (const float*)d_in[11];
    const float* w_gen   = (const float*)d_in[12];
    const float* b_gen   = (const float*)d_in[13];
    float* out = (float*)d_out;

    const size_t MB = 1024 * 1024;
    char* ws = (char*)d_ws;
    ushort_t* Hb     = (ushort_t*)ws;                          // 16 MB  [0,16)
    ushort_t* B2g    = (ushort_t*)(ws + 16 * MB);              // 3 MB   [16,19)
    ushort_t* B2i    = (ushort_t*)(ws + 19 * MB);              // 384 KB
    ushort_t* w2hb   = (ushort_t*)(ws + 19 * MB + 512 * 1024); // 128 KB
    ushort_t* w_genP = (ushort_t*)(ws + 19 * MB + 768 * 1024); // 96 KB
    float*    cbuf   = (float*)(ws + 20 * MB);                 // 1 MB   [20,21)
    float*    hbuf   = (float*)(ws + 21 * MB);                 // 1 MB   [21,22)
    ushort_t* A2     = (ushort_t*)(ws + 22 * MB);              // 2 MB   [22,24)
    ushort_t* encA2  = (ushort_t*)(ws + 27 * MB);              // 32 MB  [27,59)
    ushort_t* hseq2  = (ushort_t*)(ws + 27 * MB);              // 26 MB, overlays encA2
    ushort_t* encb   = (ushort_t*)(ws + 59 * MB);              // 16 MB  [59,75)
    float*    zbase  = cbuf;                                   // zero {c,h,A2} = 4 MB

    prep_all<<<3904, 256, 0, stream>>>(w_ih, w_hh, w_i2h, w_h2h, enc, w_gen,
                                       B2g, B2i, w2hb, encA2, encb, w_genP, zbase);
    hproj_pipe<<<dim3(512, 4), 256, 0, stream>>>(encA2, B2i, Hb);

    for (int s = 0; s < NSTEP; s++) {
        attn_full<<<512, 256, 0, stream>>>(hbuf, w2hb, b_h2h, w_score,
                                           encb, Hb, A2);
        gates_lstm<<<256, 256, 0, stream>>>(A2, B2g, b_ih, b_hh, w_ih, text,
                                            cbuf, hbuf, A2, hseq2, s);
    }
    probs_mfma<<<416, 256, 0, stream>>>(hseq2, w_genP, b_gen, out);
}

// Round 18
// 841.673 us; speedup vs baseline: 3.0519x; 1.0574x over previous
//
#include <hip/hip_runtime.h>

#define NB 1024   // batch
#define TT 32     // encoder length
#define DIN 256   // input dim
#define HD 256    // hidden dim
#define NC 38     // classes
#define NSTEP 26  // decode steps

typedef unsigned short ushort_t;
typedef __attribute__((ext_vector_type(8))) short bf16x8;
typedef __attribute__((ext_vector_type(8))) unsigned short us8;
typedef __attribute__((ext_vector_type(4))) float f32x4;

#define GLOAD_LDS16(g, l) \
  __builtin_amdgcn_global_load_lds((const __attribute__((address_space(1))) unsigned int*)(g), \
                                   (__attribute__((address_space(3))) unsigned int*)(l), 16, 0, 0)

__device__ __forceinline__ unsigned short f2bf(float x) {
    union { float f; unsigned u; } v; v.f = x;
    unsigned r = v.u + 0x7fff + ((v.u >> 16) & 1);   // RNE
    return (unsigned short)(r >> 16);
}
__device__ __forceinline__ float bf2f(unsigned short h) {
    union { unsigned u; float f; } v; v.u = ((unsigned)h) << 16;
    return v.f;
}
__device__ __forceinline__ float fast_tanh(float x) {
    float xc = fminf(fmaxf(x, -15.f), 15.f);
    float z = __expf(2.f * xc);
    return (z - 1.f) * __builtin_amdgcn_rcpf(z + 1.f);
}
__device__ __forceinline__ float fast_sig(float x) {
    return __builtin_amdgcn_rcpf(1.f + __expf(-x));
}

// ---------------------------------------------------------------------------
// prep_all: 3904 blocks.  (verbatim round 16/17, proven)
// ---------------------------------------------------------------------------
__global__ __launch_bounds__(256) void prep_all(
    const float* __restrict__ w_ih, const float* __restrict__ w_hh,
    const float* __restrict__ w_i2h, const float* __restrict__ w_h2h,
    const float* __restrict__ enc, const float* __restrict__ w_gen,
    ushort_t* __restrict__ B2g, ushort_t* __restrict__ B2i,
    ushort_t* __restrict__ w2hb, ushort_t* __restrict__ encA2,
    ushort_t* __restrict__ encb, ushort_t* __restrict__ w_genP,
    float* __restrict__ zbase)
{
    const int bid = blockIdx.x, tid = threadIdx.x;
    if (bid < 1024) {
        int j = bid;
        int jorig = ((j & 3) << 8) + (j >> 2);   // gate-interleaved cols
        for (int k = tid; k < 512; k += 256) {
            float x = (k < 256) ? w_ih[(size_t)jorig * 294 + k]
                                : w_hh[(size_t)jorig * 256 + (k - 256)];
            unsigned short hi = f2bf(x);
            unsigned short lo = f2bf(x - bf2f(hi));
            size_t r = (size_t)j * 1536;
            B2g[r + k] = hi; B2g[r + 512 + k] = lo; B2g[r + 1024 + k] = hi;
        }
    } else if (bid < 1280) {
        int n = bid - 1024;
        float x = w_i2h[(size_t)n * 256 + tid];
        unsigned short hi = f2bf(x);
        unsigned short lo = f2bf(x - bf2f(hi));
        size_t r = (size_t)n * 768;
        B2i[r + tid] = hi; B2i[r + 256 + tid] = lo; B2i[r + 512 + tid] = hi;
    } else if (bid < 1536) {
        int j = bid - 1280;
        w2hb[(size_t)j * 256 + tid] = f2bf(w_h2h[(size_t)j * 256 + tid]);
    } else if (bid < 3584) {
        int base = (bid - 1536) * 16;
#pragma unroll
        for (int rr = 0; rr < 16; rr++) {
            size_t row = base + rr;
            float x = enc[row * 256 + tid];
            unsigned short hi = f2bf(x);
            unsigned short lo = f2bf(x - bf2f(hi));
            encA2[row * 512 + tid] = hi;
            encA2[row * 512 + 256 + tid] = lo;
            encb[row * 256 + tid] = hi;
        }
    } else if (bid < 3648) {
        int j = bid - 3584;
        float x = (j < NC) ? w_gen[(size_t)j * 256 + tid] : 0.f;
        unsigned short hi = f2bf(x);
        unsigned short lo = f2bf(x - bf2f(hi));
        size_t r = (size_t)j * 768;
        w_genP[r + tid] = hi; w_genP[r + 256 + tid] = lo; w_genP[r + 512 + tid] = hi;
    } else {
        float* z = zbase + (size_t)(bid - 3648) * 4096;
        const float4 f4z = make_float4(0.f, 0.f, 0.f, 0.f);
#pragma unroll
        for (int k = 0; k < 4; k++)
            *(float4*)&z[(tid + k * 256) * 4] = f4z;
    }
}

// ---------------------------------------------------------------------------
// hproj_pipe: Hb[m][n] = bf16( sum_k enc[m][k]*w_i2h[n][k] )   (proven)
// ---------------------------------------------------------------------------
__global__ __launch_bounds__(256) void hproj_pipe(
    const ushort_t* __restrict__ encA2, const ushort_t* __restrict__ B2i,
    ushort_t* __restrict__ Hb)
{
    __shared__ ushort_t lA[2][64 * 128];
    __shared__ ushort_t lB[2][64 * 128];

    const int tid = threadIdx.x;
    const int lane = tid & 63, wid = tid >> 6;
    const int wm = wid >> 1, wn = wid & 1;
    const int m0 = blockIdx.x * 64, n0 = blockIdx.y * 64;

    f32x4 acc[2][2];
    const f32x4 fz = {0.f, 0.f, 0.f, 0.f};
    acc[0][0] = fz; acc[0][1] = fz; acc[1][0] = fz; acc[1][1] = fz;

    auto stage = [&](int t, int buf) {
#pragma unroll
        for (int i = 0; i < 4; i++) {
            int cpos = tid + i * 256;
            int m = cpos >> 4, p = cpos & 15;
            int g = p ^ (m & 7);
            int vk = t * 128 + g * 8;
            int acol = (vk < 256) ? vk : vk - 256;
            GLOAD_LDS16(&encA2[(size_t)(m0 + m) * 512 + acol], &lA[buf][cpos * 8]);
        }
#pragma unroll
        for (int i = 0; i < 4; i++) {
            int cpos = tid + i * 256;
            int n = cpos >> 4, p = cpos & 15;
            int g = p ^ (n & 7);
            GLOAD_LDS16(&B2i[(size_t)(n0 + n) * 768 + t * 128 + g * 8], &lB[buf][cpos * 8]);
        }
    };

    stage(0, 0);
    stage(1, 1);

    for (int t = 0; t < 6; t++) {
        int cur = t & 1;
        if (t < 5) asm volatile("s_waitcnt vmcnt(8)" ::: "memory");
        else       asm volatile("s_waitcnt vmcnt(0)" ::: "memory");
        __syncthreads();
#pragma unroll
        for (int kk = 0; kk < 4; kk++) {
            int g = kk * 4 + (lane >> 4);
            bf16x8 af[2], bfr[2];
#pragma unroll
            for (int mi = 0; mi < 2; mi++) {
                int m = wm * 32 + mi * 16 + (lane & 15);
                af[mi] = *(const bf16x8*)&lA[cur][m * 128 + ((g ^ (m & 7)) << 3)];
            }
#pragma unroll
            for (int ni = 0; ni < 2; ni++) {
                int n = wn * 32 + ni * 16 + (lane & 15);
                bfr[ni] = *(const bf16x8*)&lB[cur][n * 128 + ((g ^ (n & 7)) << 3)];
            }
#pragma unroll
            for (int mi = 0; mi < 2; mi++)
#pragma unroll
                for (int ni = 0; ni < 2; ni++)
                    acc[mi][ni] = __builtin_amdgcn_mfma_f32_16x16x32_bf16(af[mi], bfr[ni], acc[mi][ni], 0, 0, 0);
        }
        __syncthreads();
        if (t + 2 < 6) stage(t + 2, cur);
    }

    const int r4 = (lane >> 4) * 4;
#pragma unroll
    for (int mi = 0; mi < 2; mi++)
#pragma unroll
        for (int r = 0; r < 4; r++) {
            size_t row = m0 + wm * 32 + mi * 16 + r4 + r;
#pragma unroll
            for (int ni = 0; ni < 2; ni++) {
                int col = n0 + wn * 32 + ni * 16 + (lane & 15);
                Hb[row * 256 + col] = f2bf(acc[mi][ni][r]);
            }
        }
}

// ---------------------------------------------------------------------------
// gates_lstm: gates GEMM + fused LSTM epilogue.  BM=32: 512 blocks (2/CU),
// LDS 48 KB.  6 staging loads/thread -> counted vmcnt(6).
// Tile 32x64; 4 waves of 16x32 (acc[2]).  n-panel XCD-pinned.
// ---------------------------------------------------------------------------
__global__ __launch_bounds__(256) void gates_lstm(
    const ushort_t* __restrict__ A2in, const ushort_t* __restrict__ B2,
    const float* __restrict__ b_ih, const float* __restrict__ b_hh,
    const float* __restrict__ w_ih, const int* __restrict__ text,
    float* __restrict__ c, float* __restrict__ h,
    ushort_t* __restrict__ A2out, ushort_t* __restrict__ hseq2,
    int step)
{
    __shared__ ushort_t lA[2][32 * 128];   // 8 KB x2
    __shared__ ushort_t lB[2][64 * 128];   // 16 KB x2

    const int tid = threadIdx.x;
    const int bid = blockIdx.x;
    const int xcd = bid & 7;
    const int m0 = (bid >> 4) * 32;
    const int n0 = (xcd * 2 + ((bid >> 3) & 1)) * 64;
    const int lane = tid & 63, wid = tid >> 6;
    const int wm = wid >> 1, wn = wid & 1;

    f32x4 acc[2];
    const f32x4 fz = {0.f, 0.f, 0.f, 0.f};
    acc[0] = fz; acc[1] = fz;

    auto stage = [&](int t, int buf) {
#pragma unroll
        for (int i = 0; i < 2; i++) {
            int cpos = tid + i * 256;          // 0..511
            int m = cpos >> 4, p = cpos & 15;
            int g = p ^ (m & 7);
            int vk = t * 128 + g * 8;
            int acol = (vk < 512) ? vk : vk - 512;
            GLOAD_LDS16(&A2in[(size_t)(m0 + m) * 1024 + acol], &lA[buf][cpos * 8]);
        }
#pragma unroll
        for (int i = 0; i < 4; i++) {
            int cpos = tid + i * 256;          // 0..1023
            int n = cpos >> 4, p = cpos & 15;
            int g = p ^ (n & 7);
            GLOAD_LDS16(&B2[(size_t)(n0 + n) * 1536 + t * 128 + g * 8], &lB[buf][cpos * 8]);
        }
    };

    stage(0, 0);
    stage(1, 1);

    for (int t = 0; t < 12; t++) {
        int cur = t & 1;
        if (t < 11) asm volatile("s_waitcnt vmcnt(6)" ::: "memory");
        else        asm volatile("s_waitcnt vmcnt(0)" ::: "memory");
        __syncthreads();
        {
            int m = wm * 16 + (lane & 15);
#pragma unroll
            for (int kk = 0; kk < 4; kk++) {
                int g = kk * 4 + (lane >> 4);
                bf16x8 a0 = *(const bf16x8*)&lA[cur][m * 128 + ((g ^ (m & 7)) << 3)];
#pragma unroll
                for (int ni = 0; ni < 2; ni++) {
                    int n = wn * 32 + ni * 16 + (lane & 15);
                    bf16x8 bq = *(const bf16x8*)&lB[cur][n * 128 + ((g ^ (n & 7)) << 3)];
                    acc[ni] = __builtin_amdgcn_mfma_f32_16x16x32_bf16(a0, bq, acc[ni], 0, 0, 0);
                }
            }
        }
        __syncthreads();
        if (t + 2 < 12) stage(t + 2, cur);
    }

    // ---- epilogue 1: gates tile (32x64) -> LDS (bias + onehot) ----
    float* ltile = (float*)&lA[0][0];   // 8 KB = lA[0]
    const int r4 = (lane >> 4) * 4;
#pragma unroll
    for (int ni = 0; ni < 2; ni++) {
        int colg = n0 + wn * 32 + ni * 16 + (lane & 15);
        int jorig = ((colg & 3) << 8) + (colg >> 2);
        float bsum = b_ih[jorig] + b_hh[jorig];
        const float* wcol = &w_ih[(size_t)jorig * 294 + 256];
        int col_l = colg - n0;
#pragma unroll
        for (int r = 0; r < 4; r++) {
            int row_l = wm * 16 + r4 + r;
            int cl = text[(m0 + row_l) * NSTEP + step];
            ltile[row_l * 64 + col_l] = acc[ni][r] + bsum + wcol[cl];
        }
    }
    __syncthreads();

    // ---- epilogue 2: LSTM for 32 rows x 16 hh ----
    const int hh0 = n0 >> 2;
#pragma unroll
    for (int it = 0; it < 2; it++) {
        int idx = tid + it * 256;
        int row_l = idx >> 4, hl = idx & 15;
        int row = m0 + row_l;
        int hh = hh0 + hl;
        float gi = ltile[row_l * 64 + hl * 4 + 0];
        float gf = ltile[row_l * 64 + hl * 4 + 1];
        float gg = ltile[row_l * 64 + hl * 4 + 2];
        float go = ltile[row_l * 64 + hl * 4 + 3];
        float cv = c[(size_t)row * HD + hh];
        float cn = fast_sig(gf) * cv + fast_sig(gi) * fast_tanh(gg);
        float hn = fast_sig(go) * fast_tanh(cn);
        c[(size_t)row * HD + hh] = cn;
        h[(size_t)row * HD + hh] = hn;
        unsigned short hi_ = f2bf(hn);
        unsigned short lo_ = f2bf(hn - bf2f(hi_));
        A2out[(size_t)row * 1024 + 256 + hh] = hi_;
        A2out[(size_t)row * 1024 + 768 + hh] = lo_;
        size_t hr = ((size_t)step * NB + row) * 512;
        hseq2[hr + hh] = hi_;
        hseq2[hr + 256 + hh] = lo_;
    }
}

// ---------------------------------------------------------------------------
// attn_full: hp + scores + softmax + ctx + A2 ctx-parts.
// 256 blocks x 256 threads, FOUR rows per block (w2hb traffic 32 MB/step,
// 4/8-way ILP chains).  XCD-pinned: rows xcd*128 + 4j .. +3.
// ---------------------------------------------------------------------------
__global__ __launch_bounds__(256) void attn_full(
    const float* __restrict__ h,
    const ushort_t* __restrict__ w2hb, const float* __restrict__ b_h2h,
    const float* __restrict__ w_score,
    const ushort_t* __restrict__ encb, const ushort_t* __restrict__ Hb,
    ushort_t* __restrict__ A2)
{
    __shared__ float hsh[4][HD];
    __shared__ float hpsh[4][HD];
    __shared__ float wssh[HD];
    __shared__ float esh[4][TT];
    __shared__ float psh[4][2][HD + 1];

    const int tid = threadIdx.x;
    const int bid = blockIdx.x;
    const int b0 = (bid & 7) * 128 + (bid >> 3) * 4;

    wssh[tid] = w_score[tid];
#pragma unroll
    for (int it = 0; it < 4; it++) {
        int idx = tid + it * 256;
        int row = idx >> 8, d = idx & 255;
        hsh[row][d] = h[(size_t)(b0 + row) * HD + d];
    }
    __syncthreads();

    // hp for 4 rows; 8 independent accumulator chains
    {
        const ushort_t* wr = &w2hb[(size_t)tid * HD];
        float a[4] = {0.f, 0.f, 0.f, 0.f};
        float b[4] = {0.f, 0.f, 0.f, 0.f};
#pragma unroll 2
        for (int d = 0; d < HD; d += 16) {
            us8 w0 = *(const us8*)&wr[d];
            us8 w1 = *(const us8*)&wr[d + 8];
#pragma unroll
            for (int k = 0; k < 8; k++) {
                float f0 = bf2f(w0[k]), f1 = bf2f(w1[k]);
#pragma unroll
                for (int r = 0; r < 4; r++) {
                    a[r] += f0 * hsh[r][d + k];
                    b[r] += f1 * hsh[r][d + 8 + k];
                }
            }
        }
        float bb = b_h2h[tid];
#pragma unroll
        for (int r = 0; r < 4; r++)
            hpsh[r][tid] = a[r] + b[r] + bb;
    }
    __syncthreads();

    // scores: 2 threads per (row,t), 128 d each; 2 partial e chains
    {
        int pr = tid >> 1, q = tid & 1;
        int row = pr >> 5, t = pr & 31;
        int d0 = q * 128;
        const ushort_t* hr = &Hb[((size_t)(b0 + row) * TT + t) * HD + d0];
        const float* hp = &hpsh[row][d0];
        const float* wp = &wssh[d0];
        float e0 = 0.f, e1 = 0.f;
#pragma unroll
        for (int jj = 0; jj < 16; jj += 2) {
            us8 hv0 = *(const us8*)&hr[jj * 8];
            us8 hv1 = *(const us8*)&hr[jj * 8 + 8];
#pragma unroll
            for (int k = 0; k < 8; k++) {
                e0 += wp[jj * 8 + k] * fast_tanh(bf2f(hv0[k]) + hp[jj * 8 + k]);
                e1 += wp[jj * 8 + 8 + k] * fast_tanh(bf2f(hv1[k]) + hp[jj * 8 + 8 + k]);
            }
        }
        float e = e0 + e1;
        e += __shfl_xor(e, 1);
        if (q == 0) esh[row][t] = e;
    }
    __syncthreads();

    // softmax over 32 t, 4 rows on 32-lane groups (2 waves)
    if (tid < 128) {
        int row = tid >> 5, l = tid & 31;
        float v = esh[row][l];
        float m = v;
#pragma unroll
        for (int o = 16; o > 0; o >>= 1) m = fmaxf(m, __shfl_xor(m, o));
        float p = __expf(v - m);
        float ssum = p;
#pragma unroll
        for (int o = 16; o > 0; o >>= 1) ssum += __shfl_xor(ssum, o);
        esh[row][l] = p * __builtin_amdgcn_rcpf(ssum);
    }
    __syncthreads();

    // context: 64 threads/row, 2 groups of 16 t, 8 d per thread
    {
        int row = tid >> 6, rem = tid & 63;
        int g = rem >> 5, l = rem & 31;
        float pp[8] = {0.f, 0.f, 0.f, 0.f, 0.f, 0.f, 0.f, 0.f};
#pragma unroll
        for (int tt = 0; tt < 16; tt++) {
            int t = g * 16 + tt;
            float a = esh[row][t];
            us8 ev = *(const us8*)&encb[((size_t)(b0 + row) * TT + t) * DIN + l * 8];
#pragma unroll
            for (int k = 0; k < 8; k++)
                pp[k] += a * bf2f(ev[k]);
        }
#pragma unroll
        for (int k = 0; k < 8; k++)
            psh[row][g][l * 8 + k] = pp[k];
    }
    __syncthreads();
#pragma unroll
    for (int it = 0; it < 4; it++) {
        int idx = tid + it * 256;
        int row = idx >> 8, d = idx & 255;
        float a = psh[row][0][d] + psh[row][1][d];
        unsigned short hi_ = f2bf(a);
        A2[(size_t)(b0 + row) * 1024 + d] = hi_;
        A2[(size_t)(b0 + row) * 1024 + 512 + d] = f2bf(a - bf2f(hi_));
    }
}

// ---------------------------------------------------------------------------
// probs_mfma: probs = hseq2 @ w_genP.T  (split-bf16, virtual K=768)
// (verbatim round 16/17, proven)
// ---------------------------------------------------------------------------
__global__ __launch_bounds__(256) void probs_mfma(
    const ushort_t* __restrict__ hseq2, const ushort_t* __restrict__ w_genP,
    const float* __restrict__ b_gen, float* __restrict__ probs)
{
    __shared__ ushort_t lA[2][64 * 128];
    __shared__ ushort_t lB[2][64 * 128];

    const int tid = threadIdx.x;
    const int lane = tid & 63, wid = tid >> 6;
    const int wm = wid >> 1, wn = wid & 1;
    const int m0 = blockIdx.x * 64;

    f32x4 acc[2][2];
    const f32x4 fz = {0.f, 0.f, 0.f, 0.f};
    acc[0][0] = fz; acc[0][1] = fz; acc[1][0] = fz; acc[1][1] = fz;

    auto stage = [&](int t, int buf) {
#pragma unroll
        for (int i = 0; i < 4; i++) {
            int cpos = tid + i * 256;
            int m = cpos >> 4, p = cpos & 15;
            int g = p ^ (m & 7);
            int vk = t * 128 + g * 8;
            int acol = (vk < 256) ? vk : vk - 256;
            GLOAD_LDS16(&hseq2[(size_t)(m0 + m) * 512 + acol], &lA[buf][cpos * 8]);
        }
#pragma unroll
        for (int i = 0; i < 4; i++) {
            int cpos = tid + i * 256;
            int n = cpos >> 4, p = cpos & 15;
            int g = p ^ (n & 7);
            GLOAD_LDS16(&w_genP[(size_t)n * 768 + t * 128 + g * 8], &lB[buf][cpos * 8]);
        }
    };

    stage(0, 0);
    stage(1, 1);

    for (int t = 0; t < 6; t++) {
        int cur = t & 1;
        if (t < 5) asm volatile("s_waitcnt vmcnt(8)" ::: "memory");
        else       asm volatile("s_waitcnt vmcnt(0)" ::: "memory");
        __syncthreads();
#pragma unroll
        for (int kk = 0; kk < 4; kk++) {
            int g = kk * 4 + (lane >> 4);
            bf16x8 af[2], bfr[2];
#pragma unroll
            for (int mi = 0; mi < 2; mi++) {
                int m = wm * 32 + mi * 16 + (lane & 15);
                af[mi] = *(const bf16x8*)&lA[cur][m * 128 + ((g ^ (m & 7)) << 3)];
            }
#pragma unroll
            for (int ni = 0; ni < 2; ni++) {
                int n = wn * 32 + ni * 16 + (lane & 15);
                bfr[ni] = *(const bf16x8*)&lB[cur][n * 128 + ((g ^ (n & 7)) << 3)];
            }
#pragma unroll
            for (int mi = 0; mi < 2; mi++)
#pragma unroll
                for (int ni = 0; ni < 2; ni++)
                    acc[mi][ni] = __builtin_amdgcn_mfma_f32_16x16x32_bf16(af[mi], bfr[ni], acc[mi][ni], 0, 0, 0);
        }
        __syncthreads();
        if (t + 2 < 6) stage(t + 2, cur);
    }

    const int r4 = (lane >> 4) * 4;
    const int s = blockIdx.x >> 4;
    const int b0 = (blockIdx.x & 15) * 64;
#pragma unroll
    for (int ni = 0; ni < 2; ni++) {
        int col = wn * 32 + ni * 16 + (lane & 15);
        if (col < NC) {
            float bb = b_gen[col];
#pragma unroll
            for (int mi = 0; mi < 2; mi++)
#pragma unroll
                for (int r = 0; r < 4; r++) {
                    int b = b0 + wm * 32 + mi * 16 + r4 + r;
                    probs[((size_t)b * NSTEP + s) * NC + col] = acc[mi][ni][r] + bb;
                }
        }
    }
}

// ---------------------------------------------------------------------------
extern "C" void kernel_launch(void* const* d_in, const int* in_sizes, int n_in,
                              void* d_out, int out_size, void* d_ws, size_t ws_size,
                              hipStream_t stream)
{
    const float* enc     = (const float*)d_in[0];
    const int*   text    = (const int*)d_in[1];
    const float* w_i2h   = (const float*)d_in[4];
    const float* w_h2h   = (const float*)d_in[5];
    const float* b_h2h   = (const float*)d_in[6];
    const float* w_score = (const float*)d_in[7];
    const float* w_ih    = (const float*)d_in[8];
    const float* w_hh    = (const float*)d_in[9];
    const float* b_ih    = (const float*)d_in[10];
    const float* b_hh    = (const float*)d_in[11];
    const float* w_gen   = (const float*)d_in[12];
    const float* b_gen   = (const float*)d_in[13];
    float* out = (float*)d_out;

    const size_t MB = 1024 * 1024;
    char* ws = (char*)d_ws;
    ushort_t* Hb     = (ushort_t*)ws;                          // 16 MB  [0,16)
    ushort_t* B2g    = (ushort_t*)(ws + 16 * MB);              // 3 MB   [16,19)
    ushort_t* B2i    = (ushort_t*)(ws + 19 * MB);              // 384 KB
    ushort_t* w2hb   = (ushort_t*)(ws + 19 * MB + 512 * 1024); // 128 KB
    ushort_t* w_genP = (ushort_t*)(ws + 19 * MB + 768 * 1024); // 96 KB
    float*    cbuf   = (float*)(ws + 20 * MB);                 // 1 MB   [20,21)
    float*    hbuf   = (float*)(ws + 21 * MB);                 // 1 MB   [21,22)
    ushort_t* A2     = (ushort_t*)(ws + 22 * MB);              // 2 MB   [22,24)
    ushort_t* encA2  = (ushort_t*)(ws + 27 * MB);              // 32 MB  [27,59)
    ushort_t* hseq2  = (ushort_t*)(ws + 27 * MB);              // 26 MB, overlays encA2
    ushort_t* encb   = (ushort_t*)(ws + 59 * MB);              // 16 MB  [59,75)
    float*    zbase  = cbuf;                                   // zero {c,h,A2} = 4 MB

    prep_all<<<3904, 256, 0, stream>>>(w_ih, w_hh, w_i2h, w_h2h, enc, w_gen,
                                       B2g, B2i, w2hb, encA2, encb, w_genP, zbase);
    hproj_pipe<<<dim3(512, 4), 256, 0, stream>>>(encA2, B2i, Hb);

    for (int s = 0; s < NSTEP; s++) {
        attn_full<<<256, 256, 0, stream>>>(hbuf, w2hb, b_h2h, w_score,
                                           encb, Hb, A2);
        gates_lstm<<<512, 256, 0, stream>>>(A2, B2g, b_ih, b_hh, w_ih, text,
                                            cbuf, hbuf, A2, hseq2, s);
    }
    probs_mfma<<<416, 256, 0, stream>>>(hseq2, w_genP, b_gen, out);
}

// Round 19
// 816.767 us; speedup vs baseline: 3.1449x; 1.0305x over previous
//
#include <hip/hip_runtime.h>

#define NB 1024   // batch
#define TT 32     // encoder length
#define DIN 256   // input dim
#define HD 256    // hidden dim
#define NC 38     // classes
#define NSTEP 26  // decode steps

typedef unsigned short ushort_t;
typedef __attribute__((ext_vector_type(8))) short bf16x8;
typedef __attribute__((ext_vector_type(8))) unsigned short us8;
typedef __attribute__((ext_vector_type(4))) float f32x4;

#define GLOAD_LDS16(g, l) \
  __builtin_amdgcn_global_load_lds((const __attribute__((address_space(1))) unsigned int*)(g), \
                                   (__attribute__((address_space(3))) unsigned int*)(l), 16, 0, 0)

__device__ __forceinline__ unsigned short f2bf(float x) {
    union { float f; unsigned u; } v; v.f = x;
    unsigned r = v.u + 0x7fff + ((v.u >> 16) & 1);   // RNE
    return (unsigned short)(r >> 16);
}
__device__ __forceinline__ float bf2f(unsigned short h) {
    union { unsigned u; float f; } v; v.u = ((unsigned)h) << 16;
    return v.f;
}
__device__ __forceinline__ float fast_tanh(float x) {
    float xc = fminf(fmaxf(x, -15.f), 15.f);
    float z = __expf(2.f * xc);
    return (z - 1.f) * __builtin_amdgcn_rcpf(z + 1.f);
}
__device__ __forceinline__ float fast_sig(float x) {
    return __builtin_amdgcn_rcpf(1.f + __expf(-x));
}

// ---------------------------------------------------------------------------
// prep_all: 3904 blocks.  (verbatim, proven)
// ---------------------------------------------------------------------------
__global__ __launch_bounds__(256) void prep_all(
    const float* __restrict__ w_ih, const float* __restrict__ w_hh,
    const float* __restrict__ w_i2h, const float* __restrict__ w_h2h,
    const float* __restrict__ enc, const float* __restrict__ w_gen,
    ushort_t* __restrict__ B2g, ushort_t* __restrict__ B2i,
    ushort_t* __restrict__ w2hb, ushort_t* __restrict__ encA2,
    ushort_t* __restrict__ encb, ushort_t* __restrict__ w_genP,
    float* __restrict__ zbase)
{
    const int bid = blockIdx.x, tid = threadIdx.x;
    if (bid < 1024) {
        int j = bid;
        int jorig = ((j & 3) << 8) + (j >> 2);   // gate-interleaved cols
        for (int k = tid; k < 512; k += 256) {
            float x = (k < 256) ? w_ih[(size_t)jorig * 294 + k]
                                : w_hh[(size_t)jorig * 256 + (k - 256)];
            unsigned short hi = f2bf(x);
            unsigned short lo = f2bf(x - bf2f(hi));
            size_t r = (size_t)j * 1536;
            B2g[r + k] = hi; B2g[r + 512 + k] = lo; B2g[r + 1024 + k] = hi;
        }
    } else if (bid < 1280) {
        int n = bid - 1024;
        float x = w_i2h[(size_t)n * 256 + tid];
        unsigned short hi = f2bf(x);
        unsigned short lo = f2bf(x - bf2f(hi));
        size_t r = (size_t)n * 768;
        B2i[r + tid] = hi; B2i[r + 256 + tid] = lo; B2i[r + 512 + tid] = hi;
    } else if (bid < 1536) {
        int j = bid - 1280;
        w2hb[(size_t)j * 256 + tid] = f2bf(w_h2h[(size_t)j * 256 + tid]);
    } else if (bid < 3584) {
        int base = (bid - 1536) * 16;
#pragma unroll
        for (int rr = 0; rr < 16; rr++) {
            size_t row = base + rr;
            float x = enc[row * 256 + tid];
            unsigned short hi = f2bf(x);
            unsigned short lo = f2bf(x - bf2f(hi));
            encA2[row * 512 + tid] = hi;
            encA2[row * 512 + 256 + tid] = lo;
            encb[row * 256 + tid] = hi;
        }
    } else if (bid < 3648) {
        int j = bid - 3584;
        float x = (j < NC) ? w_gen[(size_t)j * 256 + tid] : 0.f;
        unsigned short hi = f2bf(x);
        unsigned short lo = f2bf(x - bf2f(hi));
        size_t r = (size_t)j * 768;
        w_genP[r + tid] = hi; w_genP[r + 256 + tid] = lo; w_genP[r + 512 + tid] = hi;
    } else {
        float* z = zbase + (size_t)(bid - 3648) * 4096;
        const float4 f4z = make_float4(0.f, 0.f, 0.f, 0.f);
#pragma unroll
        for (int k = 0; k < 4; k++)
            *(float4*)&z[(tid + k * 256) * 4] = f4z;
    }
}

// ---------------------------------------------------------------------------
// hproj_pipe: Hb[m][n] = bf16( sum_k enc[m][k]*w_i2h[n][k] )   (proven)
// ---------------------------------------------------------------------------
__global__ __launch_bounds__(256) void hproj_pipe(
    const ushort_t* __restrict__ encA2, const ushort_t* __restrict__ B2i,
    ushort_t* __restrict__ Hb)
{
    __shared__ ushort_t lA[2][64 * 128];
    __shared__ ushort_t lB[2][64 * 128];

    const int tid = threadIdx.x;
    const int lane = tid & 63, wid = tid >> 6;
    const int wm = wid >> 1, wn = wid & 1;
    const int m0 = blockIdx.x * 64, n0 = blockIdx.y * 64;

    f32x4 acc[2][2];
    const f32x4 fz = {0.f, 0.f, 0.f, 0.f};
    acc[0][0] = fz; acc[0][1] = fz; acc[1][0] = fz; acc[1][1] = fz;

    auto stage = [&](int t, int buf) {
#pragma unroll
        for (int i = 0; i < 4; i++) {
            int cpos = tid + i * 256;
            int m = cpos >> 4, p = cpos & 15;
            int g = p ^ (m & 7);
            int vk = t * 128 + g * 8;
            int acol = (vk < 256) ? vk : vk - 256;
            GLOAD_LDS16(&encA2[(size_t)(m0 + m) * 512 + acol], &lA[buf][cpos * 8]);
        }
#pragma unroll
        for (int i = 0; i < 4; i++) {
            int cpos = tid + i * 256;
            int n = cpos >> 4, p = cpos & 15;
            int g = p ^ (n & 7);
            GLOAD_LDS16(&B2i[(size_t)(n0 + n) * 768 + t * 128 + g * 8], &lB[buf][cpos * 8]);
        }
    };

    stage(0, 0);
    stage(1, 1);

    for (int t = 0; t < 6; t++) {
        int cur = t & 1;
        if (t < 5) asm volatile("s_waitcnt vmcnt(8)" ::: "memory");
        else       asm volatile("s_waitcnt vmcnt(0)" ::: "memory");
        __syncthreads();
#pragma unroll
        for (int kk = 0; kk < 4; kk++) {
            int g = kk * 4 + (lane >> 4);
            bf16x8 af[2], bfr[2];
#pragma unroll
            for (int mi = 0; mi < 2; mi++) {
                int m = wm * 32 + mi * 16 + (lane & 15);
                af[mi] = *(const bf16x8*)&lA[cur][m * 128 + ((g ^ (m & 7)) << 3)];
            }
#pragma unroll
            for (int ni = 0; ni < 2; ni++) {
                int n = wn * 32 + ni * 16 + (lane & 15);
                bfr[ni] = *(const bf16x8*)&lB[cur][n * 128 + ((g ^ (n & 7)) << 3)];
            }
#pragma unroll
            for (int mi = 0; mi < 2; mi++)
#pragma unroll
                for (int ni = 0; ni < 2; ni++)
                    acc[mi][ni] = __builtin_amdgcn_mfma_f32_16x16x32_bf16(af[mi], bfr[ni], acc[mi][ni], 0, 0, 0);
        }
        __syncthreads();
        if (t + 2 < 6) stage(t + 2, cur);
    }

    const int r4 = (lane >> 4) * 4;
#pragma unroll
    for (int mi = 0; mi < 2; mi++)
#pragma unroll
        for (int r = 0; r < 4; r++) {
            size_t row = m0 + wm * 32 + mi * 16 + r4 + r;
#pragma unroll
            for (int ni = 0; ni < 2; ni++) {
                int col = n0 + wn * 32 + ni * 16 + (lane & 15);
                Hb[row * 256 + col] = f2bf(acc[mi][ni][r]);
            }
        }
}

// ---------------------------------------------------------------------------
// gates_lstm: gates GEMM + fused LSTM epilogue.  BM=32, 512 blocks (2/CU).
// (verbatim round 18, proven)
// ---------------------------------------------------------------------------
__global__ __launch_bounds__(256) void gates_lstm(
    const ushort_t* __restrict__ A2in, const ushort_t* __restrict__ B2,
    const float* __restrict__ b_ih, const float* __restrict__ b_hh,
    const float* __restrict__ w_ih, const int* __restrict__ text,
    float* __restrict__ c, float* __restrict__ h,
    ushort_t* __restrict__ A2out, ushort_t* __restrict__ hseq2,
    int step)
{
    __shared__ ushort_t lA[2][32 * 128];   // 8 KB x2
    __shared__ ushort_t lB[2][64 * 128];   // 16 KB x2

    const int tid = threadIdx.x;
    const int bid = blockIdx.x;
    const int xcd = bid & 7;
    const int m0 = (bid >> 4) * 32;
    const int n0 = (xcd * 2 + ((bid >> 3) & 1)) * 64;
    const int lane = tid & 63, wid = tid >> 6;
    const int wm = wid >> 1, wn = wid & 1;

    f32x4 acc[2];
    const f32x4 fz = {0.f, 0.f, 0.f, 0.f};
    acc[0] = fz; acc[1] = fz;

    auto stage = [&](int t, int buf) {
#pragma unroll
        for (int i = 0; i < 2; i++) {
            int cpos = tid + i * 256;          // 0..511
            int m = cpos >> 4, p = cpos & 15;
            int g = p ^ (m & 7);
            int vk = t * 128 + g * 8;
            int acol = (vk < 512) ? vk : vk - 512;
            GLOAD_LDS16(&A2in[(size_t)(m0 + m) * 1024 + acol], &lA[buf][cpos * 8]);
        }
#pragma unroll
        for (int i = 0; i < 4; i++) {
            int cpos = tid + i * 256;          // 0..1023
            int n = cpos >> 4, p = cpos & 15;
            int g = p ^ (n & 7);
            GLOAD_LDS16(&B2[(size_t)(n0 + n) * 1536 + t * 128 + g * 8], &lB[buf][cpos * 8]);
        }
    };

    stage(0, 0);
    stage(1, 1);

    for (int t = 0; t < 12; t++) {
        int cur = t & 1;
        if (t < 11) asm volatile("s_waitcnt vmcnt(6)" ::: "memory");
        else        asm volatile("s_waitcnt vmcnt(0)" ::: "memory");
        __syncthreads();
        {
            int m = wm * 16 + (lane & 15);
#pragma unroll
            for (int kk = 0; kk < 4; kk++) {
                int g = kk * 4 + (lane >> 4);
                bf16x8 a0 = *(const bf16x8*)&lA[cur][m * 128 + ((g ^ (m & 7)) << 3)];
#pragma unroll
                for (int ni = 0; ni < 2; ni++) {
                    int n = wn * 32 + ni * 16 + (lane & 15);
                    bf16x8 bq = *(const bf16x8*)&lB[cur][n * 128 + ((g ^ (n & 7)) << 3)];
                    acc[ni] = __builtin_amdgcn_mfma_f32_16x16x32_bf16(a0, bq, acc[ni], 0, 0, 0);
                }
            }
        }
        __syncthreads();
        if (t + 2 < 12) stage(t + 2, cur);
    }

    // ---- epilogue 1: gates tile (32x64) -> LDS (bias + onehot) ----
    float* ltile = (float*)&lA[0][0];   // 8 KB = lA[0]
    const int r4 = (lane >> 4) * 4;
#pragma unroll
    for (int ni = 0; ni < 2; ni++) {
        int colg = n0 + wn * 32 + ni * 16 + (lane & 15);
        int jorig = ((colg & 3) << 8) + (colg >> 2);
        float bsum = b_ih[jorig] + b_hh[jorig];
        const float* wcol = &w_ih[(size_t)jorig * 294 + 256];
        int col_l = colg - n0;
#pragma unroll
        for (int r = 0; r < 4; r++) {
            int row_l = wm * 16 + r4 + r;
            int cl = text[(m0 + row_l) * NSTEP + step];
            ltile[row_l * 64 + col_l] = acc[ni][r] + bsum + wcol[cl];
        }
    }
    __syncthreads();

    // ---- epilogue 2: LSTM for 32 rows x 16 hh ----
    const int hh0 = n0 >> 2;
#pragma unroll
    for (int it = 0; it < 2; it++) {
        int idx = tid + it * 256;
        int row_l = idx >> 4, hl = idx & 15;
        int row = m0 + row_l;
        int hh = hh0 + hl;
        float gi = ltile[row_l * 64 + hl * 4 + 0];
        float gf = ltile[row_l * 64 + hl * 4 + 1];
        float gg = ltile[row_l * 64 + hl * 4 + 2];
        float go = ltile[row_l * 64 + hl * 4 + 3];
        float cv = c[(size_t)row * HD + hh];
        float cn = fast_sig(gf) * cv + fast_sig(gi) * fast_tanh(gg);
        float hn = fast_sig(go) * fast_tanh(cn);
        c[(size_t)row * HD + hh] = cn;
        h[(size_t)row * HD + hh] = hn;
        unsigned short hi_ = f2bf(hn);
        unsigned short lo_ = f2bf(hn - bf2f(hi_));
        A2out[(size_t)row * 1024 + 256 + hh] = hi_;
        A2out[(size_t)row * 1024 + 768 + hh] = lo_;
        size_t hr = ((size_t)step * NB + row) * 512;
        hseq2[hr + hh] = hi_;
        hseq2[hr + 256 + hh] = lo_;
    }
}

// ---------------------------------------------------------------------------
// attn_full: hp + scores + softmax + ctx + A2 ctx-parts.
// 256 blocks x 512 THREADS, 4 rows/block: 8 waves/CU (2/SIMD) for latency
// hiding; w2hb traffic unchanged (32 MB/step).  XCD-pinned rows.
// ---------------------------------------------------------------------------
__global__ __launch_bounds__(512) void attn_full(
    const float* __restrict__ h,
    const ushort_t* __restrict__ w2hb, const float* __restrict__ b_h2h,
    const float* __restrict__ w_score,
    const ushort_t* __restrict__ encb, const ushort_t* __restrict__ Hb,
    ushort_t* __restrict__ A2)
{
    __shared__ float hsh[4][HD];          // 4 KB
    __shared__ float hpp[2][4][HD];       // 8 KB  (hp partials)
    __shared__ float hpsh[4][HD];         // 4 KB
    __shared__ float wssh[HD];            // 1 KB
    __shared__ float esh[4][TT];          // 0.5 KB
    __shared__ float psh[4][4][HD + 1];   // 16.1 KB

    const int tid = threadIdx.x;
    const int bid = blockIdx.x;
    const int b0 = (bid & 7) * 128 + (bid >> 3) * 4;

    if (tid < 256) wssh[tid] = w_score[tid];
#pragma unroll
    for (int it = 0; it < 2; it++) {
        int idx = tid + it * 512;
        int row = idx >> 8, d = idx & 255;
        hsh[row][d] = h[(size_t)(b0 + row) * HD + d];
    }
    __syncthreads();

    // hp partials: 2 threads per j (half d-range each), 4 rows, 8 chains
    {
        int j = tid & 255, half = tid >> 8;
        const ushort_t* wr = &w2hb[(size_t)j * HD + half * 128];
        float a[4] = {0.f, 0.f, 0.f, 0.f};
        float b[4] = {0.f, 0.f, 0.f, 0.f};
#pragma unroll 2
        for (int d = 0; d < 128; d += 16) {
            us8 w0 = *(const us8*)&wr[d];
            us8 w1 = *(const us8*)&wr[d + 8];
#pragma unroll
            for (int k = 0; k < 8; k++) {
                float f0 = bf2f(w0[k]), f1 = bf2f(w1[k]);
                int dd = half * 128 + d + k;
#pragma unroll
                for (int r = 0; r < 4; r++) {
                    a[r] += f0 * hsh[r][dd];
                    b[r] += f1 * hsh[r][dd + 8];
                }
            }
        }
#pragma unroll
        for (int r = 0; r < 4; r++)
            hpp[half][r][j] = a[r] + b[r];
    }
    __syncthreads();
    // combine hp partials + bias
#pragma unroll
    for (int it = 0; it < 2; it++) {
        int idx = tid + it * 512;
        int r = idx >> 8, j = idx & 255;
        hpsh[r][j] = hpp[0][r][j] + hpp[1][r][j] + b_h2h[j];
    }
    __syncthreads();

    // scores: 4 threads per (row,t), 64 d each; 2 partial e chains
    {
        int pr = tid >> 2, q = tid & 3;
        int row = pr >> 5, t = pr & 31;
        int d0 = q * 64;
        const ushort_t* hr = &Hb[((size_t)(b0 + row) * TT + t) * HD + d0];
        const float* hp = &hpsh[row][d0];
        const float* wp = &wssh[d0];
        float e0 = 0.f, e1 = 0.f;
#pragma unroll
        for (int jj = 0; jj < 8; jj += 2) {
            us8 hv0 = *(const us8*)&hr[jj * 8];
            us8 hv1 = *(const us8*)&hr[jj * 8 + 8];
#pragma unroll
            for (int k = 0; k < 8; k++) {
                e0 += wp[jj * 8 + k] * fast_tanh(bf2f(hv0[k]) + hp[jj * 8 + k]);
                e1 += wp[jj * 8 + 8 + k] * fast_tanh(bf2f(hv1[k]) + hp[jj * 8 + 8 + k]);
            }
        }
        float e = e0 + e1;
        e += __shfl_xor(e, 1);
        e += __shfl_xor(e, 2);
        if (q == 0) esh[row][t] = e;
    }
    __syncthreads();

    // softmax over 32 t, 4 rows on 32-lane groups (2 waves)
    if (tid < 128) {
        int row = tid >> 5, l = tid & 31;
        float v = esh[row][l];
        float m = v;
#pragma unroll
        for (int o = 16; o > 0; o >>= 1) m = fmaxf(m, __shfl_xor(m, o));
        float p = __expf(v - m);
        float ssum = p;
#pragma unroll
        for (int o = 16; o > 0; o >>= 1) ssum += __shfl_xor(ssum, o);
        esh[row][l] = p * __builtin_amdgcn_rcpf(ssum);
    }
    __syncthreads();

    // context: 128 threads/row, 4 groups of 8 t, 8 d per thread
    {
        int row = tid >> 7, rem = tid & 127;
        int g = rem >> 5, l = rem & 31;
        float pp[8] = {0.f, 0.f, 0.f, 0.f, 0.f, 0.f, 0.f, 0.f};
#pragma unroll
        for (int tt = 0; tt < 8; tt++) {
            int t = g * 8 + tt;
            float a = esh[row][t];
            us8 ev = *(const us8*)&encb[((size_t)(b0 + row) * TT + t) * DIN + l * 8];
#pragma unroll
            for (int k = 0; k < 8; k++)
                pp[k] += a * bf2f(ev[k]);
        }
#pragma unroll
        for (int k = 0; k < 8; k++)
            psh[row][g][l * 8 + k] = pp[k];
    }
    __syncthreads();
#pragma unroll
    for (int it = 0; it < 2; it++) {
        int idx = tid + it * 512;
        int row = idx >> 8, d = idx & 255;
        float a = psh[row][0][d] + psh[row][1][d] + psh[row][2][d] + psh[row][3][d];
        unsigned short hi_ = f2bf(a);
        A2[(size_t)(b0 + row) * 1024 + d] = hi_;
        A2[(size_t)(b0 + row) * 1024 + 512 + d] = f2bf(a - bf2f(hi_));
    }
}

// ---------------------------------------------------------------------------
// probs_mfma: probs = hseq2 @ w_genP.T  (split-bf16, virtual K=768)
// (verbatim, proven)
// ---------------------------------------------------------------------------
__global__ __launch_bounds__(256) void probs_mfma(
    const ushort_t* __restrict__ hseq2, const ushort_t* __restrict__ w_genP,
    const float* __restrict__ b_gen, float* __restrict__ probs)
{
    __shared__ ushort_t lA[2][64 * 128];
    __shared__ ushort_t lB[2][64 * 128];

    const int tid = threadIdx.x;
    const int lane = tid & 63, wid = tid >> 6;
    const int wm = wid >> 1, wn = wid & 1;
    const int m0 = blockIdx.x * 64;

    f32x4 acc[2][2];
    const f32x4 fz = {0.f, 0.f, 0.f, 0.f};
    acc[0][0] = fz; acc[0][1] = fz; acc[1][0] = fz; acc[1][1] = fz;

    auto stage = [&](int t, int buf) {
#pragma unroll
        for (int i = 0; i < 4; i++) {
            int cpos = tid + i * 256;
            int m = cpos >> 4, p = cpos & 15;
            int g = p ^ (m & 7);
            int vk = t * 128 + g * 8;
            int acol = (vk < 256) ? vk : vk - 256;
            GLOAD_LDS16(&hseq2[(size_t)(m0 + m) * 512 + acol], &lA[buf][cpos * 8]);
        }
#pragma unroll
        for (int i = 0; i < 4; i++) {
            int cpos = tid + i * 256;
            int n = cpos >> 4, p = cpos & 15;
            int g = p ^ (n & 7);
            GLOAD_LDS16(&w_genP[(size_t)n * 768 + t * 128 + g * 8], &lB[buf][cpos * 8]);
        }
    };

    stage(0, 0);
    stage(1, 1);

    for (int t = 0; t < 6; t++) {
        int cur = t & 1;
        if (t < 5) asm volatile("s_waitcnt vmcnt(8)" ::: "memory");
        else       asm volatile("s_waitcnt vmcnt(0)" ::: "memory");
        __syncthreads();
#pragma unroll
        for (int kk = 0; kk < 4; kk++) {
            int g = kk * 4 + (lane >> 4);
            bf16x8 af[2], bfr[2];
#pragma unroll
            for (int mi = 0; mi < 2; mi++) {
                int m = wm * 32 + mi * 16 + (lane & 15);
                af[mi] = *(const bf16x8*)&lA[cur][m * 128 + ((g ^ (m & 7)) << 3)];
            }
#pragma unroll
            for (int ni = 0; ni < 2; ni++) {
                int n = wn * 32 + ni * 16 + (lane & 15);
                bfr[ni] = *(const bf16x8*)&lB[cur][n * 128 + ((g ^ (n & 7)) << 3)];
            }
#pragma unroll
            for (int mi = 0; mi < 2; mi++)
#pragma unroll
                for (int ni = 0; ni < 2; ni++)
                    acc[mi][ni] = __builtin_amdgcn_mfma_f32_16x16x32_bf16(af[mi], bfr[ni], acc[mi][ni], 0, 0, 0);
        }
        __syncthreads();
        if (t + 2 < 6) stage(t + 2, cur);
    }

    const int r4 = (lane >> 4) * 4;
    const int s = blockIdx.x >> 4;
    const int b0 = (blockIdx.x & 15) * 64;
#pragma unroll
    for (int ni = 0; ni < 2; ni++) {
        int col = wn * 32 + ni * 16 + (lane & 15);
        if (col < NC) {
            float bb = b_gen[col];
#pragma unroll
            for (int mi = 0; mi < 2; mi++)
#pragma unroll
                for (int r = 0; r < 4; r++) {
                    int b = b0 + wm * 32 + mi * 16 + r4 + r;
                    probs[((size_t)b * NSTEP + s) * NC + col] = acc[mi][ni][r] + bb;
                }
        }
    }
}

// ---------------------------------------------------------------------------
extern "C" void kernel_launch(void* const* d_in, const int* in_sizes, int n_in,
                              void* d_out, int out_size, void* d_ws, size_t ws_size,
                              hipStream_t stream)
{
    const float* enc     = (const float*)d_in[0];
    const int*   text    = (const int*)d_in[1];
    const float* w_i2h   = (const float*)d_in[4];
    const float* w_h2h   = (const float*)d_in[5];
    const float* b_h2h   = (const float*)d_in[6];
    const float* w_score = (const float*)d_in[7];
    const float* w_ih    = (const float*)d_in[8];
    const float* w_hh    = (const float*)d_in[9];
    const float* b_ih    = (const float*)d_in[10];
    const float* b_hh    = (const float*)d_in[11];
    const float* w_gen   = (const float*)d_in[12];
    const float* b_gen   = (const float*)d_in[13];
    float* out = (float*)d_out;

    const size_t MB = 1024 * 1024;
    char* ws = (char*)d_ws;
    ushort_t* Hb     = (ushort_t*)ws;                          // 16 MB  [0,16)
    ushort_t* B2g    = (ushort_t*)(ws + 16 * MB);              // 3 MB   [16,19)
    ushort_t* B2i    = (ushort_t*)(ws + 19 * MB);              // 384 KB
    ushort_t* w2hb   = (ushort_t*)(ws + 19 * MB + 512 * 1024); // 128 KB
    ushort_t* w_genP = (ushort_t*)(ws + 19 * MB + 768 * 1024); // 96 KB
    float*    cbuf   = (float*)(ws + 20 * MB);                 // 1 MB   [20,21)
    float*    hbuf   = (float*)(ws + 21 * MB);                 // 1 MB   [21,22)
    ushort_t* A2     = (ushort_t*)(ws + 22 * MB);              // 2 MB   [22,24)
    ushort_t* encA2  = (ushort_t*)(ws + 27 * MB);              // 32 MB  [27,59)
    ushort_t* hseq2  = (ushort_t*)(ws + 27 * MB);              // 26 MB, overlays encA2
    ushort_t* encb   = (ushort_t*)(ws + 59 * MB);              // 16 MB  [59,75)
    float*    zbase  = cbuf;                                   // zero {c,h,A2} = 4 MB

    prep_all<<<3904, 256, 0, stream>>>(w_ih, w_hh, w_i2h, w_h2h, enc, w_gen,
                                       B2g, B2i, w2hb, encA2, encb, w_genP, zbase);
    hproj_pipe<<<dim3(512, 4), 256, 0, stream>>>(encA2, B2i, Hb);

    for (int s = 0; s < NSTEP; s++) {
        attn_full<<<256, 512, 0, stream>>>(hbuf, w2hb, b_h2h, w_score,
                                           encb, Hb, A2);
        gates_lstm<<<512, 256, 0, stream>>>(A2, B2g, b_ih, b_hh, w_ih, text,
                                            cbuf, hbuf, A2, hseq2, s);
    }
    probs_mfma<<<416, 256, 0, stream>>>(hseq2, w_genP, b_gen, out);
}